// Round 7
// baseline (9778.032 us; speedup 1.0000x reference)
//
#include <hip/hip_runtime.h>
#include <hip/hip_bf16.h>

typedef __hip_bfloat16 bf16;
typedef __attribute__((ext_vector_type(4))) short short4v;
typedef __attribute__((ext_vector_type(8))) short short8v;
typedef __attribute__((ext_vector_type(4))) float f32x4;

#define B_   16
#define L_   512
#define HR   300
#define DM_  600
#define DK_  75
#define MAXA 8

// ---------------------------------------------------------------- embed
// embs layout: [seq = b*L+t][360]
__global__ __launch_bounds__(256) void k_embed(
    const int* __restrict__ tok, const int* __restrict__ pos, const int* __restrict__ post,
    const float* __restrict__ emb_w, const float* __restrict__ pos_w, const float* __restrict__ post_w,
    float* __restrict__ embs)
{
  int idx = blockIdx.x * 256 + threadIdx.x;
  if (idx >= L_ * B_ * 360) return;
  int d = idx % 360;
  int si = idx / 360;
  float v;
  if (d < 300)       v = emb_w[(long)tok[si] * 300 + d];
  else if (d < 330)  v = pos_w[pos[si] * 30 + (d - 300)];
  else               v = post_w[post[si] * 30 + (d - 330)];
  embs[idx] = v;
}

// ---------------------------------------------------------------- MFMA GEMM (bf16x3 split)
// C[M,N] = alpha * A[M,K] @ (NT ? B[N,K]^T : B[K,N]) (+bias,+bias2) (/rowdiv) (relu)
// 64x64 tile, 4 waves; wave w owns rows w*16..w*16+15.
// Fragment layouts (gfx950 16x16x32 bf16):
//   A/B: lane l, elem j -> k = (j>=4)*16 + (l>>4)*4 + (j&3); idx16 = l&15 (row of A / col of B)
//   C/D: col = l&15, row = (l>>4)*4 + reg   [m89-verified]
__device__ inline short2 splitf(float x) {
  bf16 h = __float2bfloat16(x);
  float r = x - __bfloat162float(h);
  bf16 l2 = __float2bfloat16(r);
  short2 out;
  out.x = *reinterpret_cast<short*>(&h);
  out.y = *reinterpret_cast<short*>(&l2);
  return out;
}

__device__ inline short8v ld_frag(const short* p) {
  short4v a = *reinterpret_cast<const short4v*>(p);
  short4v b = *reinterpret_cast<const short4v*>(p + 16);
  short8v r;
  r[0]=a[0]; r[1]=a[1]; r[2]=a[2]; r[3]=a[3];
  r[4]=b[0]; r[5]=b[1]; r[6]=b[2]; r[7]=b[3];
  return r;
}

#define LDA_ 36   // row stride in shorts (32 + 4 pad -> conflict-free b64 reads)

template<bool NT>
__global__ __launch_bounds__(256) void k_mgemm(
    const float* __restrict__ A, int lda, long sA1, long sA2,
    const float* __restrict__ Bm, int ldb, long sB1, long sB2,
    float* __restrict__ C, bf16* __restrict__ Cbf, int ldc, long sC1, long sC2,
    const float* __restrict__ bias, const float* __restrict__ bias2,
    const float* __restrict__ rowdiv,
    float alpha, int relu, int M, int N, int K, int nb2)
{
  __shared__ short Ah[64 * LDA_], Al[64 * LDA_], Bh[64 * LDA_], Bl[64 * LDA_];
  const int tid = threadIdx.x;
  const int w = tid >> 6, l = tid & 63;
  const int z = blockIdx.z;
  const int b1 = z / nb2, b2 = z - b1 * nb2;
  const float* Ab = A + b1 * sA1 + b2 * sA2;
  const float* Bb = Bm + b1 * sB1 + b2 * sB2;
  const int row0 = blockIdx.y * 64, col0 = blockIdx.x * 64;

  f32x4 acc[4];
#pragma unroll
  for (int c = 0; c < 4; ++c) acc[c] = (f32x4){0.f, 0.f, 0.f, 0.f};

  const int lrow = l & 15, lk = (l >> 4) * 4;

  for (int k0 = 0; k0 < K; k0 += 32) {
    // ---- stage A: rows row0.., 32 k ----
#pragma unroll
    for (int i = 0; i < 2; ++i) {
      int slot = tid * 2 + i;
      int r = slot >> 3, kq = slot & 7;
      int gr = row0 + r, gk = k0 + kq * 4;
      float v[4] = {0.f, 0.f, 0.f, 0.f};
      if (gr < M) {
        if (gk + 3 < K) {
          float4 t = *reinterpret_cast<const float4*>(Ab + (long)gr * lda + gk);
          v[0] = t.x; v[1] = t.y; v[2] = t.z; v[3] = t.w;
        } else {
#pragma unroll
          for (int q = 0; q < 4; ++q) if (gk + q < K) v[q] = Ab[(long)gr * lda + gk + q];
        }
      }
      short4v hv, lv;
#pragma unroll
      for (int q = 0; q < 4; ++q) {
        short2 t2 = splitf(v[q]);
        hv[q] = t2.x; lv[q] = t2.y;
      }
      *reinterpret_cast<short4v*>(&Ah[r * LDA_ + kq * 4]) = hv;
      *reinterpret_cast<short4v*>(&Al[r * LDA_ + kq * 4]) = lv;
    }
    // ---- stage B ----
    if (NT) {
#pragma unroll
      for (int i = 0; i < 2; ++i) {
        int slot = tid * 2 + i;
        int r = slot >> 3, kq = slot & 7;
        int gc = col0 + r, gk = k0 + kq * 4;
        float v[4] = {0.f, 0.f, 0.f, 0.f};
        if (gc < N) {
          if (gk + 3 < K) {
            float4 t = *reinterpret_cast<const float4*>(Bb + (long)gc * ldb + gk);
            v[0] = t.x; v[1] = t.y; v[2] = t.z; v[3] = t.w;
          } else {
#pragma unroll
            for (int q = 0; q < 4; ++q) if (gk + q < K) v[q] = Bb[(long)gc * ldb + gk + q];
          }
        }
        short4v hv, lv;
#pragma unroll
        for (int q = 0; q < 4; ++q) {
          short2 t2 = splitf(v[q]);
          hv[q] = t2.x; lv[q] = t2.y;
        }
        *reinterpret_cast<short4v*>(&Bh[r * LDA_ + kq * 4]) = hv;
        *reinterpret_cast<short4v*>(&Bl[r * LDA_ + kq * 4]) = lv;
      }
    } else {
#pragma unroll
      for (int i = 0; i < 2; ++i) {
        int slot = tid * 2 + i;
        int kk = slot >> 4, nq = slot & 15;
        int gk = k0 + kk, gn = col0 + nq * 4;
        float v[4] = {0.f, 0.f, 0.f, 0.f};
        if (gk < K) {
          if (gn + 3 < N) {
            float4 t = *reinterpret_cast<const float4*>(Bb + (long)gk * ldb + gn);
            v[0] = t.x; v[1] = t.y; v[2] = t.z; v[3] = t.w;
          } else {
#pragma unroll
            for (int q = 0; q < 4; ++q) if (gn + q < N) v[q] = Bb[(long)gk * ldb + gn + q];
          }
        }
#pragma unroll
        for (int q = 0; q < 4; ++q) {
          short2 t2 = splitf(v[q]);
          Bh[(nq * 4 + q) * LDA_ + kk] = t2.x;
          Bl[(nq * 4 + q) * LDA_ + kk] = t2.y;
        }
      }
    }
    __syncthreads();

    // ---- compute ----
    const short* ap  = &Ah[(w * 16 + lrow) * LDA_ + lk];
    const short* alp = &Al[(w * 16 + lrow) * LDA_ + lk];
    short8v ah = ld_frag(ap);
    short8v al = ld_frag(alp);
#pragma unroll
    for (int c = 0; c < 4; ++c) {
      const short* bp  = &Bh[(c * 16 + lrow) * LDA_ + lk];
      const short* blp = &Bl[(c * 16 + lrow) * LDA_ + lk];
      short8v bh = ld_frag(bp);
      short8v bl = ld_frag(blp);
      acc[c] = __builtin_amdgcn_mfma_f32_16x16x32_bf16(ah, bh, acc[c], 0, 0, 0);
      acc[c] = __builtin_amdgcn_mfma_f32_16x16x32_bf16(ah, bl, acc[c], 0, 0, 0);
      acc[c] = __builtin_amdgcn_mfma_f32_16x16x32_bf16(al, bh, acc[c], 0, 0, 0);
    }
    __syncthreads();
  }

  // ---- epilogue ----
  float* Cb = C ? C + b1 * sC1 + b2 * sC2 : (float*)0;
  bf16*  Cf = Cbf ? Cbf + b1 * sC1 + b2 * sC2 : (bf16*)0;
#pragma unroll
  for (int c = 0; c < 4; ++c) {
    int cc = col0 + c * 16 + lrow;
    if (cc >= N) continue;
#pragma unroll
    for (int reg = 0; reg < 4; ++reg) {
      int r = row0 + w * 16 + (l >> 4) * 4 + reg;
      if (r >= M) continue;
      float v = acc[c][reg] * alpha;
      if (bias) v += bias[cc];
      if (bias2) v += bias2[cc];
      if (rowdiv) v /= rowdiv[(long)z * M + r];
      if (relu) v = fmaxf(v, 0.f);
      if (Cf) Cf[(long)r * ldc + cc] = __float2bfloat16(v);
      else    Cb[(long)r * ldc + cc] = v;
    }
  }
}

// ---------------------------------------------------------------- W_hh k-blocked transpose
// dst[(k>>2)*4800 + j*4 + (k&3)] = src[j*300+k]  (per dir)
__global__ __launch_bounds__(256) void k_wtrans(
    const float* __restrict__ whh_f, const float* __restrict__ whh_b,
    float* __restrict__ wbf, float* __restrict__ wbb)
{
  int idx = blockIdx.x * 256 + threadIdx.x;
  if (idx >= 2 * 360000) return;
  int d = idx / 360000;
  int e = idx - d * 360000;
  int j = e / 300, k = e - j * 300;
  const float* src = d ? whh_b : whh_f;
  float* dst = d ? wbb : wbf;
  dst[(k >> 2) * 4800 + j * 4 + (k & 3)] = src[e];
}

// ---------------------------------------------------------------- BiLSTM: one block per (dir,batch)
// No inter-block communication. W_hh streamed from L2 each step (k-blocked
// float4 layout, coalesced). h broadcast from LDS, c in registers.
// pre: [b*L+t][1200] with biases folded. 512 threads: rows {t, t+512, t+1024(t<176)}.
__global__ __launch_bounds__(512, 1) void k_lstm2(
    const float* __restrict__ pre_f, const float* __restrict__ pre_b,
    const float* __restrict__ wb_f, const float* __restrict__ wb_b,
    float* __restrict__ gcn)
{
  const int tid = threadIdx.x;
  const int dir = blockIdx.x & 1;
  const int b   = blockIdx.x >> 1;
  const float* pre = (dir ? pre_b : pre_f) + (long)b * L_ * 1200;
  const float4* wb = reinterpret_cast<const float4*>(dir ? wb_b : wb_f);

  __shared__ float h_lds[304];
  __shared__ float g_lds[1216];

  const int r0 = tid, r1 = tid + 512, r2 = tid + 1024;
  const bool has2 = (tid < 176);
  float c_reg = 0.f;

  for (int i = tid; i < 304; i += 512) h_lds[i] = 0.f;
  __syncthreads();

#pragma unroll 1
  for (int s = 0; s < L_; ++s) {
    const int tf = dir ? (L_ - 1 - s) : s;
    const float* prow = pre + (long)tf * 1200;
    float a0 = prow[r0];
    float a1 = prow[r1];
    float a2 = has2 ? prow[r2] : 0.f;

    if (s > 0) {
      const float4* h4 = reinterpret_cast<const float4*>(h_lds);
#pragma unroll 5
      for (int k4 = 0; k4 < 75; ++k4) {
        float4 hv = h4[k4];
        float4 w0 = wb[(long)k4 * 1200 + r0];
        float4 w1 = wb[(long)k4 * 1200 + r1];
        a0 = fmaf(w0.x, hv.x, a0); a0 = fmaf(w0.y, hv.y, a0);
        a0 = fmaf(w0.z, hv.z, a0); a0 = fmaf(w0.w, hv.w, a0);
        a1 = fmaf(w1.x, hv.x, a1); a1 = fmaf(w1.y, hv.y, a1);
        a1 = fmaf(w1.z, hv.z, a1); a1 = fmaf(w1.w, hv.w, a1);
        if (has2) {
          float4 w2 = wb[(long)k4 * 1200 + r2];
          a2 = fmaf(w2.x, hv.x, a2); a2 = fmaf(w2.y, hv.y, a2);
          a2 = fmaf(w2.z, hv.z, a2); a2 = fmaf(w2.w, hv.w, a2);
        }
      }
    }
    g_lds[r0] = a0;
    g_lds[r1] = a1;
    if (has2) g_lds[r2] = a2;
    __syncthreads();

    if (tid < 300) {
      float gi = g_lds[tid];
      float gf = g_lds[300 + tid];
      float gg = g_lds[600 + tid];
      float go = g_lds[900 + tid];
      float si = 1.f / (1.f + __expf(-gi));
      float sf = 1.f / (1.f + __expf(-gf));
      float so = 1.f / (1.f + __expf(-go));
      float tg = tanhf(gg);
      c_reg = sf * c_reg + si * tg;
      float h = so * tanhf(c_reg);
      h_lds[tid] = h;
      gcn[((long)b * L_ + tf) * DM_ + dir * HR + tid] = h;
    }
    __syncthreads();
  }
}

// ---------------------------------------------------------------- small aspect kernels
__global__ void k_asplist(const float* __restrict__ asp_mask, int* __restrict__ apos, int* __restrict__ acnt)
{
  int b = threadIdx.x;
  if (b >= B_) return;
  int c = 0;
  for (int l = 0; l < L_; ++l)
    if (asp_mask[b * L_ + l] > 0.f) { if (c < MAXA) apos[b * MAXA + c] = l; ++c; }
  acnt[b] = (c < MAXA) ? c : MAXA;
}

__global__ void k_t0(const float* __restrict__ bd, const float* __restrict__ wm, float* __restrict__ t0)
{
  int i = blockIdx.x * 256 + threadIdx.x;
  if (i >= 8 * DK_) return;
  int h = i / DK_, e = i % DK_;
  float s = 0.f;
  for (int d = 0; d < DK_; ++d) s += bd[d] * wm[(h * DK_ + d) * DK_ + e];
  t0[i] = s;
}

__global__ void k_aspd(const float* __restrict__ gcn, const float* __restrict__ asp_mask,
                       const int* __restrict__ apos, const int* __restrict__ acnt,
                       const float* __restrict__ wd, const float* __restrict__ bd, float* __restrict__ aspd)
{
  int i = blockIdx.x * 256 + threadIdx.x;
  if (i >= B_ * MAXA * DK_) return;
  int d = i % DK_;
  int ba = i / DK_;
  int a = ba % MAXA, b = ba / MAXA;
  if (a >= acnt[b]) { aspd[i] = 0.f; return; }
  int p = apos[b * MAXA + a];
  float mv = asp_mask[b * L_ + p];
  const float* row = gcn + ((long)b * L_ + p) * DM_;
  float s = 0.f;
  for (int k = 0; k < DM_; ++k) s += row[k] * wd[d * DM_ + k];
  aspd[i] = s * mv + bd[d];
}

__global__ void k_tasp(const float* __restrict__ aspd, const int* __restrict__ acnt,
                       const float* __restrict__ wm, float* __restrict__ tasp)
{
  int i = blockIdx.x * 256 + threadIdx.x;
  if (i >= B_ * 8 * MAXA * DK_) return;
  int e = i % DK_;
  int t3 = i / DK_;
  int a = t3 % MAXA;
  int t4 = t3 / MAXA;
  int h = t4 % 8, b = t4 / 8;
  if (a >= acnt[b]) { tasp[i] = 0.f; return; }
  const float* ar = aspd + (b * MAXA + a) * DK_;
  float s = 0.f;
  for (int d = 0; d < DK_; ++d) s += ar[d] * wm[(h * DK_ + d) * DK_ + e];
  tasp[i] = s;
}

__global__ void k_avg(const float* __restrict__ k_lin, const float* __restrict__ t0,
                      const float* __restrict__ tasp, const int* __restrict__ acnt,
                      const float* __restrict__ bias_m, float* __restrict__ s0, float* __restrict__ avg)
{
  int i = blockIdx.x * 256 + threadIdx.x;
  if (i >= B_ * 8 * L_) return;
  int m = i % L_;
  int bh = i / L_;
  int h = bh % 8, b = bh / 8;
  const float* kr = k_lin + ((long)b * L_ + m) * DM_ + h * DK_;
  float bm = bias_m[0];
  const float* t0r = t0 + h * DK_;
  float d0 = 0.f;
  for (int e = 0; e < DK_; ++e) d0 += t0r[e] * kr[e];
  float sv = tanhf(d0 + bm);
  int cnt = acnt[b];
  float acc = (float)(L_ - cnt) * sv;
  for (int a = 0; a < cnt; ++a) {
    const float* tr = tasp + (((b * 8 + h) * MAXA) + a) * DK_;
    float dd = 0.f;
    for (int e = 0; e < DK_; ++e) dd += tr[e] * kr[e];
    acc += tanhf(dd + bm);
  }
  s0[i] = sv;
  avg[i] = acc * (1.f / (float)L_);
}

__global__ void k_bar(const float* __restrict__ s0, const float* __restrict__ avg,
                      float* __restrict__ s0bar, float* __restrict__ avbar)
{
  int i = blockIdx.x * 256 + threadIdx.x;
  if (i >= B_ * L_) return;
  int m = i % L_, b = i / L_;
  float sa = 0.f, aa = 0.f;
  for (int h = 0; h < 8; ++h) { sa += s0[(b * 8 + h) * L_ + m]; aa += avg[(b * 8 + h) * L_ + m]; }
  s0bar[i] = sa * 0.125f;
  avbar[i] = aa * 0.125f;
}

__global__ __launch_bounds__(256) void k_adjag(
    const float* __restrict__ asp_mask, const float* __restrict__ adjr,
    const float* __restrict__ s0bar, const float* __restrict__ avbar,
    float* __restrict__ adjag, float* __restrict__ denag)
{
  int bl = blockIdx.x;
  int b = bl >> 9, l = bl & 511;
  bool rA = asp_mask[b * L_ + l] > 0.f;
  float avl = avbar[b * L_ + l];
  float lsum = 0.f;
  for (int q = 0; q < 2; ++q) {
    int m = threadIdx.x + q * 256;
    bool cA = asp_mask[b * L_ + m] > 0.f;
    float asv;
    if (cA && (!rA || m > l)) asv = avl;
    else if (rA)              asv = avbar[b * L_ + m];
    else                      asv = s0bar[b * L_ + m];
    float r = (asv > 0.9f) ? 1.f : __expf(0.8f * adjr[((long)b * L_ + l) * L_ + m]);
    float v = r * asv;
    adjag[((long)b * L_ + l) * L_ + m] = v;
    lsum += v;
  }
  __shared__ float red[256];
  red[threadIdx.x] = lsum;
  __syncthreads();
  for (int st = 128; st > 0; st >>= 1) {
    if (threadIdx.x < st) red[threadIdx.x] += red[threadIdx.x + st];
    __syncthreads();
  }
  if (threadIdx.x == 0) denag[bl] = red[0] + 1.f;
}

__global__ __launch_bounds__(256) void k_stats(
    const bf16* __restrict__ sc, const int* __restrict__ tok,
    float* __restrict__ mx, float* __restrict__ sm)
{
  int row = blockIdx.x * 4 + (threadIdx.x >> 6);
  int lane = threadIdx.x & 63;
  if (row >= B_ * 8 * L_) return;
  int b = row >> 12;
  const bf16* p = sc + (long)row * L_;
  const int* tkb = tok + b * L_;
  float v[8];
#pragma unroll
  for (int i = 0; i < 8; ++i) {
    int m = lane * 8 + i;
    float s = __bfloat162float(p[m]);
    v[i] = (tkb[m] != 0) ? s : -1e9f;
  }
  float mxl = v[0];
#pragma unroll
  for (int i = 1; i < 8; ++i) mxl = fmaxf(mxl, v[i]);
  for (int off = 32; off > 0; off >>= 1) mxl = fmaxf(mxl, __shfl_xor(mxl, off));
  float s = 0.f;
#pragma unroll
  for (int i = 0; i < 8; ++i) s += __expf(v[i] - mxl);
  for (int off = 32; off > 0; off >>= 1) s += __shfl_xor(s, off);
  if (lane == 0) { mx[row] = mxl; sm[row] = s; }
}

__global__ __launch_bounds__(256) void k_adjs(
    const bf16* __restrict__ sc, const int* __restrict__ tok,
    const float* __restrict__ mx, const float* __restrict__ sm,
    float* __restrict__ adjs, float* __restrict__ dens)
{
  int bl = blockIdx.x;
  int b = bl >> 9, l = bl & 511;
  float acc0 = 0.f, acc1 = 0.f;
  for (int h = 0; h < 8; ++h) {
    int row = (b * 8 + h) * L_ + l;
    float mxv = mx[row];
    float inv = 1.f / sm[row];
    const bf16* p = sc + (long)row * L_;
    {
      int m = threadIdx.x;
      float s = __bfloat162float(p[m]);
      s = (tok[b * L_ + m] != 0) ? s : -1e9f;
      acc0 += __expf(s - mxv) * inv;
    }
    {
      int m = threadIdx.x + 256;
      float s = __bfloat162float(p[m]);
      s = (tok[b * L_ + m] != 0) ? s : -1e9f;
      acc1 += __expf(s - mxv) * inv;
    }
  }
  float rmask = (tok[b * L_ + l] != 0) ? 1.f : 0.f;
  float lsum = 0.f;
  {
    int m = threadIdx.x;
    float v = acc0 * 0.125f;
    v = (m == l) ? 1.f : v;
    v *= rmask;
    adjs[(long)bl * L_ + m] = v;
    lsum += v;
  }
  {
    int m = threadIdx.x + 256;
    float v = acc1 * 0.125f;
    v = (m == l) ? 1.f : v;
    v *= rmask;
    adjs[(long)bl * L_ + m] = v;
    lsum += v;
  }
  __shared__ float red[256];
  red[threadIdx.x] = lsum;
  __syncthreads();
  for (int st = 128; st > 0; st >>= 1) {
    if (threadIdx.x < st) red[threadIdx.x] += red[threadIdx.x + st];
    __syncthreads();
  }
  if (threadIdx.x == 0) dens[bl] = red[0] + 1.f;
}

__global__ __launch_bounds__(256) void k_softmax(float* __restrict__ X)
{
  long row = blockIdx.x;
  float* p = X + row * L_;
  int tid = threadIdx.x;
  float a = p[tid], b = p[tid + 256];
  __shared__ float red[256];
  red[tid] = fmaxf(a, b);
  __syncthreads();
  for (int st = 128; st > 0; st >>= 1) {
    if (tid < st) red[tid] = fmaxf(red[tid], red[tid + st]);
    __syncthreads();
  }
  float mxv = red[0];
  __syncthreads();
  float ea = __expf(a - mxv), eb = __expf(b - mxv);
  red[tid] = ea + eb;
  __syncthreads();
  for (int st = 128; st > 0; st >>= 1) {
    if (tid < st) red[tid] += red[tid + st];
    __syncthreads();
  }
  float inv = 1.f / red[0];
  p[tid] = ea * inv;
  p[tid + 256] = eb * inv;
}

// ---------------------------------------------------------------- host side
static void gemm(hipStream_t st, bool nt,
                 const float* A, int lda, long sA1, long sA2,
                 const float* Bm, int ldb, long sB1, long sB2,
                 float* C, bf16* Cbf, int ldc, long sC1, long sC2,
                 const float* bias, const float* bias2, const float* rowdiv,
                 float alpha, int relu, int M, int N, int K, int nb1, int nb2)
{
  dim3 g((N + 63) / 64, (M + 63) / 64, nb1 * nb2);
  if (nt)
    k_mgemm<true><<<g, 256, 0, st>>>(A, lda, sA1, sA2, Bm, ldb, sB1, sB2, C, Cbf, ldc, sC1, sC2,
                                     bias, bias2, rowdiv, alpha, relu, M, N, K, nb2);
  else
    k_mgemm<false><<<g, 256, 0, st>>>(A, lda, sA1, sA2, Bm, ldb, sB1, sB2, C, Cbf, ldc, sC1, sC2,
                                      bias, bias2, rowdiv, alpha, relu, M, N, K, nb2);
}

extern "C" void kernel_launch(void* const* d_in, const int* in_sizes, int n_in,
                              void* d_out, int out_size, void* d_ws, size_t ws_size,
                              hipStream_t stream)
{
  const int*   tok     = (const int*)d_in[0];
  const int*   pos     = (const int*)d_in[1];
  const int*   post    = (const int*)d_in[2];
  const float* asp_mask= (const float*)d_in[3];
  const float* adjr    = (const float*)d_in[5];
  const float* emb_w   = (const float*)d_in[6];
  const float* pos_w   = (const float*)d_in[7];
  const float* post_w  = (const float*)d_in[8];
  const float* w_ih_f  = (const float*)d_in[9];
  const float* w_hh_f  = (const float*)d_in[10];
  const float* b_ih_f  = (const float*)d_in[11];
  const float* b_hh_f  = (const float*)d_in[12];
  const float* w_ih_b  = (const float*)d_in[13];
  const float* w_hh_b  = (const float*)d_in[14];
  const float* b_ih_b  = (const float*)d_in[15];
  const float* b_hh_b  = (const float*)d_in[16];
  const float* wq      = (const float*)d_in[17];
  const float* bq      = (const float*)d_in[18];
  const float* wk      = (const float*)d_in[19];
  const float* bk      = (const float*)d_in[20];
  const float* wd      = (const float*)d_in[21];
  const float* bd      = (const float*)d_in[22];
  const float* wm      = (const float*)d_in[23];
  const float* bias_m  = (const float*)d_in[24];
  const float* wa0     = (const float*)d_in[25];
  const float* ba0     = (const float*)d_in[26];
  const float* wa1     = (const float*)d_in[27];
  const float* ba1     = (const float*)d_in[28];
  const float* ws0     = (const float*)d_in[29];
  const float* bs0     = (const float*)d_in[30];
  const float* ws1     = (const float*)d_in[31];
  const float* bs1     = (const float*)d_in[32];
  const float* aff1    = (const float*)d_in[33];
  const float* aff2    = (const float*)d_in[34];
  float* out = (float*)d_out;
  float* W = (float*)d_ws;

  // ---- workspace layout (float units) ----
  size_t off = 0;
  auto alloc = [&](size_t n) { size_t o = off; off += (n + 63) & ~(size_t)63; return o; };
  size_t o_gcn   = alloc((size_t)8192 * DM_);
  size_t o_q     = alloc((size_t)8192 * DM_);
  size_t o_k     = alloc((size_t)8192 * DM_);
  size_t o_adjs  = alloc((size_t)B_ * L_ * L_);
  size_t o_dens  = alloc(8192);
  size_t o_adjag = alloc((size_t)B_ * L_ * L_);
  size_t o_denag = alloc(8192);
  size_t o_t0    = alloc(600);
  size_t o_apos  = alloc(B_ * MAXA);
  size_t o_acnt  = alloc(64);
  size_t o_aspd  = alloc(B_ * MAXA * DK_);
  size_t o_tasp  = alloc(B_ * 8 * MAXA * DK_);
  size_t o_s0    = alloc(B_ * 8 * L_);
  size_t o_avg   = alloc(B_ * 8 * L_);
  size_t o_s0bar = alloc(B_ * L_);
  size_t o_avbar = alloc(B_ * L_);
  size_t o_mx    = alloc(B_ * 8 * L_);
  size_t o_sm    = alloc(B_ * 8 * L_);
  size_t o_wb    = alloc(2 * 360000);       // k-blocked W_hh (f, b)
  size_t o_oag1  = alloc((size_t)8192 * 300);
  size_t o_os1   = alloc((size_t)8192 * 300);
  size_t o_big   = alloc(22609920);   // union region
  size_t o_embs = o_big;
  size_t o_pref = o_big + 2949120;
  size_t o_preb = o_pref + 9830400;
  size_t o_sc   = o_big;
  size_t o_tmp  = o_big;
  size_t o_gag  = o_big + 4915200;
  size_t o_gs   = o_gag + 2457600;
  size_t o_h1   = o_gs  + 2457600;
  size_t o_a1m  = o_h1  + 2457600;
  size_t o_a2m  = o_a1m + 4194304;

  if (ws_size < off * sizeof(float)) {
    (void)hipMemsetAsync(d_out, 0x7F, (size_t)out_size * sizeof(float), stream);
    return;
  }

  // 0) W_hh -> k-blocked transposed layout
  k_wtrans<<<(2 * 360000 + 255) / 256, 256, 0, stream>>>(w_hh_f, w_hh_b, W + o_wb, W + o_wb + 360000);

  // 1) embeddings -> [b*L+t][360]
  k_embed<<<(L_ * B_ * 360 + 255) / 256, 256, 0, stream>>>(tok, pos, post, emb_w, pos_w, post_w, W + o_embs);

  // 2) pre-GEMMs: pre[(b,t)][1200] = embs @ w_ih^T + (b_ih + b_hh)
  gemm(stream, true, W + o_embs, 360, 0, 0, w_ih_f, 360, 0, 0,
       W + o_pref, nullptr, 1200, 0, 0, b_ih_f, b_hh_f, nullptr, 1.f, 0, 8192, 1200, 360, 1, 1);
  gemm(stream, true, W + o_embs, 360, 0, 0, w_ih_b, 360, 0, 0,
       W + o_preb, nullptr, 1200, 0, 0, b_ih_b, b_hh_b, nullptr, 1.f, 0, 8192, 1200, 360, 1, 1);

  // 3) BiLSTM: 32 independent (dir,batch) blocks, weights streamed from L2
  k_lstm2<<<32, 512, 0, stream>>>(W + o_pref, W + o_preb, W + o_wb, W + o_wb + 360000, W + o_gcn);

  // 4) q/k projections
  gemm(stream, true, W + o_gcn, DM_, 0, 0, wq, DM_, 0, 0,
       W + o_q, nullptr, DM_, 0, 0, bq, nullptr, nullptr, 1.f, 0, 8192, DM_, DM_, 1, 1);
  gemm(stream, true, W + o_gcn, DM_, 0, 0, wk, DM_, 0, 0,
       W + o_k, nullptr, DM_, 0, 0, bk, nullptr, nullptr, 1.f, 0, 8192, DM_, DM_, 1, 1);

  // 5) aspect structure
  k_asplist<<<1, 64, 0, stream>>>(asp_mask, (int*)(W + o_apos), (int*)(W + o_acnt));
  k_t0<<<(600 + 255) / 256, 256, 0, stream>>>(bd, wm, W + o_t0);
  k_aspd<<<(B_ * MAXA * DK_ + 255) / 256, 256, 0, stream>>>(W + o_gcn, asp_mask,
      (const int*)(W + o_apos), (const int*)(W + o_acnt), wd, bd, W + o_aspd);
  k_tasp<<<(B_ * 8 * MAXA * DK_ + 255) / 256, 256, 0, stream>>>(W + o_aspd,
      (const int*)(W + o_acnt), wm, W + o_tasp);
  k_avg<<<(B_ * 8 * L_ + 255) / 256, 256, 0, stream>>>(W + o_k, W + o_t0, W + o_tasp,
      (const int*)(W + o_acnt), bias_m, W + o_s0, W + o_avg);
  k_bar<<<(B_ * L_ + 255) / 256, 256, 0, stream>>>(W + o_s0, W + o_avg, W + o_s0bar, W + o_avbar);

  // 6) scores (bf16) -> stats -> adj_s ; adj_ag
  gemm(stream, true, W + o_q, DM_, (long)L_ * DM_, DK_, W + o_k, DM_, (long)L_ * DM_, DK_,
       nullptr, (bf16*)(W + o_sc), L_, (long)8 * L_ * L_, (long)L_ * L_,
       nullptr, nullptr, nullptr, 0.1154700538f, 0, L_, L_, DK_, B_, 8);
  k_stats<<<(B_ * 8 * L_) / 4, 256, 0, stream>>>((const bf16*)(W + o_sc), tok, W + o_mx, W + o_sm);
  k_adjs<<<B_ * L_, 256, 0, stream>>>((const bf16*)(W + o_sc), tok, W + o_mx, W + o_sm,
                                      W + o_adjs, W + o_dens);
  k_adjag<<<B_ * L_, 256, 0, stream>>>(asp_mask, adjr, W + o_s0bar, W + o_avbar,
                                       W + o_adjag, W + o_denag);

  // 7) two GCN layers
  const float* waL[2] = {wa0, wa1};
  const float* baL[2] = {ba0, ba1};
  const float* wsL[2] = {ws0, ws1};
  const float* bsL[2] = {bs0, bs1};
  const float* inAg = W + o_gcn;
  const float* inS  = W + o_gcn;
  int D = DM_;
  for (int layer = 0; layer < 2; ++layer) {
    gemm(stream, false, W + o_adjag, L_, (long)L_ * L_, 0, inAg, D, (long)L_ * D, 0,
         W + o_tmp, nullptr, D, (long)L_ * D, 0, nullptr, nullptr, nullptr, 1.f, 0, L_, D, L_, B_, 1);
    gemm(stream, true, W + o_tmp, D, 0, 0, waL[layer], D, 0, 0,
         W + o_gag, nullptr, 300, 0, 0, baL[layer], nullptr, W + o_denag, 1.f, 1, 8192, 300, D, 1, 1);
    gemm(stream, false, W + o_adjs, L_, (long)L_ * L_, 0, inS, D, (long)L_ * D, 0,
         W + o_tmp, nullptr, D, (long)L_ * D, 0, nullptr, nullptr, nullptr, 1.f, 0, L_, D, L_, B_, 1);
    gemm(stream, true, W + o_tmp, D, 0, 0, wsL[layer], D, 0, 0,
         W + o_gs, nullptr, 300, 0, 0, bsL[layer], nullptr, W + o_dens, 1.f, 1, 8192, 300, D, 1, 1);
    gemm(stream, false, W + o_gag, 300, 0, 0, aff1, 300, 0, 0,
         W + o_h1, nullptr, 300, 0, 0, nullptr, nullptr, nullptr, 1.f, 0, 8192, 300, 300, 1, 1);
    gemm(stream, true, W + o_h1, 300, (long)L_ * 300, 0, W + o_gs, 300, (long)L_ * 300, 0,
         W + o_a1m, nullptr, L_, (long)L_ * L_, 0, nullptr, nullptr, nullptr, 1.f, 0, L_, L_, 300, B_, 1);
    k_softmax<<<B_ * L_, 256, 0, stream>>>(W + o_a1m);
    gemm(stream, false, W + o_gs, 300, 0, 0, aff2, 300, 0, 0,
         W + o_h1, nullptr, 300, 0, 0, nullptr, nullptr, nullptr, 1.f, 0, 8192, 300, 300, 1, 1);
    gemm(stream, true, W + o_h1, 300, (long)L_ * 300, 0, W + o_gag, 300, (long)L_ * 300, 0,
         W + o_a2m, nullptr, L_, (long)L_ * L_, 0, nullptr, nullptr, nullptr, 1.f, 0, L_, L_, 300, B_, 1);
    k_softmax<<<B_ * L_, 256, 0, stream>>>(W + o_a2m);
    float* dstAg; float* dstS; int ldcO; long sCO;
    if (layer == 0) { dstAg = W + o_oag1; dstS = W + o_os1; ldcO = 300; sCO = (long)L_ * 300; }
    else            { dstAg = out;        dstS = out + 300; ldcO = 600; sCO = (long)L_ * 600; }
    gemm(stream, false, W + o_a1m, L_, (long)L_ * L_, 0, W + o_gs, 300, (long)L_ * 300, 0,
         dstAg, nullptr, ldcO, sCO, 0, nullptr, nullptr, nullptr, 1.f, 0, L_, 300, L_, B_, 1);
    gemm(stream, false, W + o_a2m, L_, (long)L_ * L_, 0, W + o_gag, 300, (long)L_ * 300, 0,
         dstS, nullptr, ldcO, sCO, 0, nullptr, nullptr, nullptr, 1.f, 0, L_, 300, L_, B_, 1);
    inAg = W + o_oag1;
    inS  = W + o_os1;
    D = 300;
  }
}

// Round 8
// 3498.719 us; speedup vs baseline: 2.7947x; 2.7947x over previous
//
#include <hip/hip_runtime.h>
#include <hip/hip_bf16.h>

typedef __hip_bfloat16 bf16;
typedef __attribute__((ext_vector_type(4))) short short4v;
typedef __attribute__((ext_vector_type(8))) short short8v;
typedef __attribute__((ext_vector_type(4))) float f32x4;

#define B_   16
#define L_   512
#define HR   300
#define DM_  600
#define DK_  75
#define MAXA 8
#define NCH  38            // u-chunks per dir (37*8 + 4)

// ---------------------------------------------------------------- embed
// embs layout: [seq = t*16 + b][360]
__global__ __launch_bounds__(256) void k_embed(
    const int* __restrict__ tok, const int* __restrict__ pos, const int* __restrict__ post,
    const float* __restrict__ emb_w, const float* __restrict__ pos_w, const float* __restrict__ post_w,
    float* __restrict__ embs)
{
  int idx = blockIdx.x * 256 + threadIdx.x;
  if (idx >= L_ * B_ * 360) return;
  int d = idx % 360;
  int seq = idx / 360;
  int b = seq & 15, t = seq >> 4;
  int si = b * L_ + t;
  float v;
  if (d < 300)       v = emb_w[(long)tok[si] * 300 + d];
  else if (d < 330)  v = pos_w[pos[si] * 30 + (d - 300)];
  else               v = post_w[post[si] * 30 + (d - 330)];
  embs[idx] = v;
}

// ---------------------------------------------------------------- MFMA GEMM (bf16x3 split)
__device__ inline short2 splitf(float x) {
  bf16 h = __float2bfloat16(x);
  float r = x - __bfloat162float(h);
  bf16 l2 = __float2bfloat16(r);
  short2 out;
  out.x = *reinterpret_cast<short*>(&h);
  out.y = *reinterpret_cast<short*>(&l2);
  return out;
}

__device__ inline short8v ld_frag(const short* p) {
  short4v a = *reinterpret_cast<const short4v*>(p);
  short4v b = *reinterpret_cast<const short4v*>(p + 16);
  short8v r;
  r[0]=a[0]; r[1]=a[1]; r[2]=a[2]; r[3]=a[3];
  r[4]=b[0]; r[5]=b[1]; r[6]=b[2]; r[7]=b[3];
  return r;
}

#define LDA_ 36   // row stride in shorts (32 + 4 pad)

template<bool NT>
__global__ __launch_bounds__(256) void k_mgemm(
    const float* __restrict__ A, int lda, long sA1, long sA2,
    const float* __restrict__ Bm, int ldb, long sB1, long sB2,
    float* __restrict__ C, bf16* __restrict__ Cbf, int ldc, long sC1, long sC2,
    const float* __restrict__ bias, const float* __restrict__ bias2,
    const float* __restrict__ rowdiv,
    float alpha, int relu, int M, int N, int K, int nb2)
{
  __shared__ short Ah[64 * LDA_], Al[64 * LDA_], Bh[64 * LDA_], Bl[64 * LDA_];
  const int tid = threadIdx.x;
  const int w = tid >> 6, l = tid & 63;
  const int z = blockIdx.z;
  const int b1 = z / nb2, b2 = z - b1 * nb2;
  const float* Ab = A + b1 * sA1 + b2 * sA2;
  const float* Bb = Bm + b1 * sB1 + b2 * sB2;
  const int row0 = blockIdx.y * 64, col0 = blockIdx.x * 64;

  f32x4 acc[4];
#pragma unroll
  for (int c = 0; c < 4; ++c) acc[c] = (f32x4){0.f, 0.f, 0.f, 0.f};

  const int lrow = l & 15, lk = (l >> 4) * 4;

  for (int k0 = 0; k0 < K; k0 += 32) {
#pragma unroll
    for (int i = 0; i < 2; ++i) {
      int slot = tid * 2 + i;
      int r = slot >> 3, kq = slot & 7;
      int gr = row0 + r, gk = k0 + kq * 4;
      float v[4] = {0.f, 0.f, 0.f, 0.f};
      if (gr < M) {
        if (gk + 3 < K) {
          float4 t = *reinterpret_cast<const float4*>(Ab + (long)gr * lda + gk);
          v[0] = t.x; v[1] = t.y; v[2] = t.z; v[3] = t.w;
        } else {
#pragma unroll
          for (int q = 0; q < 4; ++q) if (gk + q < K) v[q] = Ab[(long)gr * lda + gk + q];
        }
      }
      short4v hv, lv;
#pragma unroll
      for (int q = 0; q < 4; ++q) {
        short2 t2 = splitf(v[q]);
        hv[q] = t2.x; lv[q] = t2.y;
      }
      *reinterpret_cast<short4v*>(&Ah[r * LDA_ + kq * 4]) = hv;
      *reinterpret_cast<short4v*>(&Al[r * LDA_ + kq * 4]) = lv;
    }
    if (NT) {
#pragma unroll
      for (int i = 0; i < 2; ++i) {
        int slot = tid * 2 + i;
        int r = slot >> 3, kq = slot & 7;
        int gc = col0 + r, gk = k0 + kq * 4;
        float v[4] = {0.f, 0.f, 0.f, 0.f};
        if (gc < N) {
          if (gk + 3 < K) {
            float4 t = *reinterpret_cast<const float4*>(Bb + (long)gc * ldb + gk);
            v[0] = t.x; v[1] = t.y; v[2] = t.z; v[3] = t.w;
          } else {
#pragma unroll
            for (int q = 0; q < 4; ++q) if (gk + q < K) v[q] = Bb[(long)gc * ldb + gk + q];
          }
        }
        short4v hv, lv;
#pragma unroll
        for (int q = 0; q < 4; ++q) {
          short2 t2 = splitf(v[q]);
          hv[q] = t2.x; lv[q] = t2.y;
        }
        *reinterpret_cast<short4v*>(&Bh[r * LDA_ + kq * 4]) = hv;
        *reinterpret_cast<short4v*>(&Bl[r * LDA_ + kq * 4]) = lv;
      }
    } else {
#pragma unroll
      for (int i = 0; i < 2; ++i) {
        int slot = tid * 2 + i;
        int kk = slot >> 4, nq = slot & 15;
        int gk = k0 + kk, gn = col0 + nq * 4;
        float v[4] = {0.f, 0.f, 0.f, 0.f};
        if (gk < K) {
          if (gn + 3 < N) {
            float4 t = *reinterpret_cast<const float4*>(Bb + (long)gk * ldb + gn);
            v[0] = t.x; v[1] = t.y; v[2] = t.z; v[3] = t.w;
          } else {
#pragma unroll
            for (int q = 0; q < 4; ++q) if (gn + q < N) v[q] = Bb[(long)gk * ldb + gn + q];
          }
        }
#pragma unroll
        for (int q = 0; q < 4; ++q) {
          short2 t2 = splitf(v[q]);
          Bh[(nq * 4 + q) * LDA_ + kk] = t2.x;
          Bl[(nq * 4 + q) * LDA_ + kk] = t2.y;
        }
      }
    }
    __syncthreads();

    const short* ap  = &Ah[(w * 16 + lrow) * LDA_ + lk];
    const short* alp = &Al[(w * 16 + lrow) * LDA_ + lk];
    short8v ah = ld_frag(ap);
    short8v al = ld_frag(alp);
#pragma unroll
    for (int c = 0; c < 4; ++c) {
      const short* bp  = &Bh[(c * 16 + lrow) * LDA_ + lk];
      const short* blp = &Bl[(c * 16 + lrow) * LDA_ + lk];
      short8v bh = ld_frag(bp);
      short8v bl = ld_frag(blp);
      acc[c] = __builtin_amdgcn_mfma_f32_16x16x32_bf16(ah, bh, acc[c], 0, 0, 0);
      acc[c] = __builtin_amdgcn_mfma_f32_16x16x32_bf16(ah, bl, acc[c], 0, 0, 0);
      acc[c] = __builtin_amdgcn_mfma_f32_16x16x32_bf16(al, bh, acc[c], 0, 0, 0);
    }
    __syncthreads();
  }

  float* Cb = C ? C + b1 * sC1 + b2 * sC2 : (float*)0;
  bf16*  Cf = Cbf ? Cbf + b1 * sC1 + b2 * sC2 : (bf16*)0;
#pragma unroll
  for (int c = 0; c < 4; ++c) {
    int cc = col0 + c * 16 + lrow;
    if (cc >= N) continue;
#pragma unroll
    for (int reg = 0; reg < 4; ++reg) {
      int r = row0 + w * 16 + (l >> 4) * 4 + reg;
      if (r >= M) continue;
      float v = acc[c][reg] * alpha;
      if (bias) v += bias[cc];
      if (bias2) v += bias2[cc];
      if (rowdiv) v /= rowdiv[(long)z * M + r];
      if (relu) v = fmaxf(v, 0.f);
      if (Cf) Cf[(long)r * ldc + cc] = __float2bfloat16(v);
      else    Cb[(long)r * ldc + cc] = v;
    }
  }
}

// ---------------------------------------------------------------- BiLSTM
// 76 blocks = 2 dirs x 38 u-chunks. Weights sharded in VGPRs.
// h exchange via SELF-VALIDATING TAGGED WORDS (round-5 kernel, benched 2219us):
// u32 = (step_tag<<16) | bf16(h) through relaxed agent-scope atomics; readers
// poll data words until tag matches. No flags, no fences, one one-way trip/step.
__global__ __launch_bounds__(256, 1) void k_lstm(
    const float* __restrict__ preT_f, const float* __restrict__ preT_b,
    const float* __restrict__ whh_f, const float* __restrict__ whh_b,
    const float* __restrict__ bih_f, const float* __restrict__ bhh_f,
    const float* __restrict__ bih_b, const float* __restrict__ bhh_b,
    float* __restrict__ gcn, unsigned* __restrict__ hg)
{
  const int tid = threadIdx.x;
  const int dir = blockIdx.x / NCH;
  const int blk = blockIdx.x - dir * NCH;
  const int u0 = blk * 8;
  const int uc = min(8, HR - u0);
  const float* pre = dir ? preT_b : preT_f;
  const float* whh = dir ? whh_b : whh_f;
  const float* bih = dir ? bih_b : bih_f;
  const float* bhh = dir ? bhh_b : bhh_f;
  unsigned* hgd = hg + dir * 4800;              // + buf*9600

  __shared__ float4 h5[300 * 5];
  __shared__ float part[32 * 545 + 64];
  __shared__ float g_lds[512];

  const int kc = tid >> 3;
  const int rq = tid & 7;
  const int kl = (kc < 12) ? 10 : 9;
  const int k0 = kc * 9 + min(kc, 12);

  float wreg[4][10];
#pragma unroll
  for (int i = 0; i < 4; ++i) {
    int lr = rq * 4 + i;
    int gate = lr >> 3, unit = lr & 7;
    bool valid = unit < uc;
    int growc = gate * HR + u0 + min(unit, uc - 1);
#pragma unroll
    for (int kk = 0; kk < 10; ++kk) {
      int k = min(k0 + kk, 299);
      float wv = whh[(long)growc * HR + k];
      wreg[i][kk] = (valid && kk < kl) ? wv : 0.f;
    }
  }

  const int o0 = tid * 2;
  const int lr0 = o0 >> 4;
  const int b0 = o0 & 15;
  const int gate0 = lr0 >> 3, unit0 = lr0 & 7;
  const int grow0 = gate0 * HR + u0 + min(unit0, uc - 1);
  const float breg = bih[grow0] + bhh[grow0];
  const float* prebase = pre + (long)grow0 * 8192;

  const int au = tid >> 4, ab = tid & 15;
  float c_reg = 0.f;

  const int own_lo = u0 * 16, own_hi = (u0 + uc) * 16;
  float* h5f = reinterpret_cast<float*>(h5);

#pragma unroll 1
  for (int s = 0; s < L_; ++s) {
    const int tf = dir ? (L_ - 1 - s) : s;

    float p0 = prebase[tf * 16 + b0];
    float p1 = prebase[tf * 16 + b0 + 1];

    if (s > 0) {
      unsigned* srcb = hgd + (s & 1) * 9600;
      const unsigned tag = (unsigned)s;
      unsigned vals[19];
      int idxs[19];
#pragma unroll
      for (int j = 0; j < 19; ++j) {
        int idx = tid + j * 256;
        bool act = (idx < 4800) && (idx < own_lo || idx >= own_hi);
        idxs[j] = act ? idx : -1;
        vals[j] = act ? __hip_atomic_load(&srcb[idx], __ATOMIC_RELAXED, __HIP_MEMORY_SCOPE_AGENT)
                      : (tag << 16);
      }
      for (;;) {
        bool ok = true;
#pragma unroll
        for (int j = 0; j < 19; ++j)
          if ((vals[j] >> 16) != tag) ok = false;
        if (ok) break;
#pragma unroll
        for (int j = 0; j < 19; ++j)
          if ((vals[j] >> 16) != tag)
            vals[j] = __hip_atomic_load(&srcb[idxs[j]], __ATOMIC_RELAXED, __HIP_MEMORY_SCOPE_AGENT);
      }
#pragma unroll
      for (int j = 0; j < 19; ++j) {
        int idx = idxs[j];
        if (idx >= 0) {
          unsigned short hb = (unsigned short)(vals[j] & 0xffffu);
          bf16 hbf = *reinterpret_cast<bf16*>(&hb);
          h5f[(idx >> 4) * 20 + (idx & 15)] = __bfloat162float(hbf);
        }
      }
    }
    __syncthreads();

    if (s > 0) {
      float4 acc[4][4];
#pragma unroll
      for (int i = 0; i < 4; ++i)
#pragma unroll
        for (int q = 0; q < 4; ++q) acc[i][q] = make_float4(0.f, 0.f, 0.f, 0.f);
#pragma unroll
      for (int kk = 0; kk < 10; ++kk) {
        if (kk < kl) {
          int k = k0 + kk;
          float4 hb0 = h5[k * 5 + 0];
          float4 hb1 = h5[k * 5 + 1];
          float4 hb2 = h5[k * 5 + 2];
          float4 hb3 = h5[k * 5 + 3];
#pragma unroll
          for (int i = 0; i < 4; ++i) {
            float w = wreg[i][kk];
            acc[i][0].x = fmaf(w, hb0.x, acc[i][0].x); acc[i][0].y = fmaf(w, hb0.y, acc[i][0].y);
            acc[i][0].z = fmaf(w, hb0.z, acc[i][0].z); acc[i][0].w = fmaf(w, hb0.w, acc[i][0].w);
            acc[i][1].x = fmaf(w, hb1.x, acc[i][1].x); acc[i][1].y = fmaf(w, hb1.y, acc[i][1].y);
            acc[i][1].z = fmaf(w, hb1.z, acc[i][1].z); acc[i][1].w = fmaf(w, hb1.w, acc[i][1].w);
            acc[i][2].x = fmaf(w, hb2.x, acc[i][2].x); acc[i][2].y = fmaf(w, hb2.y, acc[i][2].y);
            acc[i][2].z = fmaf(w, hb2.z, acc[i][2].z); acc[i][2].w = fmaf(w, hb2.w, acc[i][2].w);
            acc[i][3].x = fmaf(w, hb3.x, acc[i][3].x); acc[i][3].y = fmaf(w, hb3.y, acc[i][3].y);
            acc[i][3].w = fmaf(w, hb3.w, acc[i][3].w); acc[i][3].z = fmaf(w, hb3.z, acc[i][3].z);
          }
        }
      }
#pragma unroll
      for (int i = 0; i < 4; ++i) {
        int lr = rq * 4 + i;
        float* pb = part + kc * 545 + lr * 17;
#pragma unroll
        for (int q = 0; q < 4; ++q) {
          pb[q * 4 + 0] = acc[i][q].x; pb[q * 4 + 1] = acc[i][q].y;
          pb[q * 4 + 2] = acc[i][q].z; pb[q * 4 + 3] = acc[i][q].w;
        }
      }
    }
    __syncthreads();

    float g0 = p0 + breg, g1 = p1 + breg;
    if (s > 0) {
      const float* pb = part + lr0 * 17 + b0;
#pragma unroll
      for (int q = 0; q < 32; ++q) { g0 += pb[q * 545]; g1 += pb[q * 545 + 1]; }
    }
    g_lds[o0] = g0; g_lds[o0 + 1] = g1;
    __syncthreads();

    if (tid < 128 && au < uc) {
      float gi = g_lds[(0 * 8 + au) * 16 + ab];
      float gf = g_lds[(1 * 8 + au) * 16 + ab];
      float gg = g_lds[(2 * 8 + au) * 16 + ab];
      float go = g_lds[(3 * 8 + au) * 16 + ab];
      float si = 1.f / (1.f + __expf(-gi));
      float sf = 1.f / (1.f + __expf(-gf));
      float so = 1.f / (1.f + __expf(-go));
      float tg = tanhf(gg);
      c_reg = sf * c_reg + si * tg;
      float h = so * tanhf(c_reg);
      h5f[(u0 + au) * 20 + ab] = h;
      bf16 hbf = __float2bfloat16(h);
      unsigned bits = *reinterpret_cast<unsigned short*>(&hbf);
      unsigned val = ((unsigned)(s + 1) << 16) | bits;
      __hip_atomic_store(&hgd[((s + 1) & 1) * 9600 + (u0 + au) * 16 + ab], val,
                         __ATOMIC_RELAXED, __HIP_MEMORY_SCOPE_AGENT);
      gcn[((long)ab * L_ + tf) * DM_ + dir * HR + u0 + au] = h;
    }
  }
}

// ---------------------------------------------------------------- small aspect kernels
__global__ void k_asplist(const float* __restrict__ asp_mask, int* __restrict__ apos, int* __restrict__ acnt)
{
  int b = threadIdx.x;
  if (b >= B_) return;
  int c = 0;
  for (int l = 0; l < L_; ++l)
    if (asp_mask[b * L_ + l] > 0.f) { if (c < MAXA) apos[b * MAXA + c] = l; ++c; }
  acnt[b] = (c < MAXA) ? c : MAXA;
}

__global__ void k_t0(const float* __restrict__ bd, const float* __restrict__ wm, float* __restrict__ t0)
{
  int i = blockIdx.x * 256 + threadIdx.x;
  if (i >= 8 * DK_) return;
  int h = i / DK_, e = i % DK_;
  float s = 0.f;
  for (int d = 0; d < DK_; ++d) s += bd[d] * wm[(h * DK_ + d) * DK_ + e];
  t0[i] = s;
}

__global__ void k_aspd(const float* __restrict__ gcn, const float* __restrict__ asp_mask,
                       const int* __restrict__ apos, const int* __restrict__ acnt,
                       const float* __restrict__ wd, const float* __restrict__ bd, float* __restrict__ aspd)
{
  int i = blockIdx.x * 256 + threadIdx.x;
  if (i >= B_ * MAXA * DK_) return;
  int d = i % DK_;
  int ba = i / DK_;
  int a = ba % MAXA, b = ba / MAXA;
  if (a >= acnt[b]) { aspd[i] = 0.f; return; }
  int p = apos[b * MAXA + a];
  float mv = asp_mask[b * L_ + p];
  const float* row = gcn + ((long)b * L_ + p) * DM_;
  float s = 0.f;
  for (int k = 0; k < DM_; ++k) s += row[k] * wd[d * DM_ + k];
  aspd[i] = s * mv + bd[d];
}

__global__ void k_tasp(const float* __restrict__ aspd, const int* __restrict__ acnt,
                       const float* __restrict__ wm, float* __restrict__ tasp)
{
  int i = blockIdx.x * 256 + threadIdx.x;
  if (i >= B_ * 8 * MAXA * DK_) return;
  int e = i % DK_;
  int t3 = i / DK_;
  int a = t3 % MAXA;
  int t4 = t3 / MAXA;
  int h = t4 % 8, b = t4 / 8;
  if (a >= acnt[b]) { tasp[i] = 0.f; return; }
  const float* ar = aspd + (b * MAXA + a) * DK_;
  float s = 0.f;
  for (int d = 0; d < DK_; ++d) s += ar[d] * wm[(h * DK_ + d) * DK_ + e];
  tasp[i] = s;
}

__global__ void k_avg(const float* __restrict__ k_lin, const float* __restrict__ t0,
                      const float* __restrict__ tasp, const int* __restrict__ acnt,
                      const float* __restrict__ bias_m, float* __restrict__ s0, float* __restrict__ avg)
{
  int i = blockIdx.x * 256 + threadIdx.x;
  if (i >= B_ * 8 * L_) return;
  int m = i % L_;
  int bh = i / L_;
  int h = bh % 8, b = bh / 8;
  const float* kr = k_lin + ((long)b * L_ + m) * DM_ + h * DK_;
  float bm = bias_m[0];
  const float* t0r = t0 + h * DK_;
  float d0 = 0.f;
  for (int e = 0; e < DK_; ++e) d0 += t0r[e] * kr[e];
  float sv = tanhf(d0 + bm);
  int cnt = acnt[b];
  float acc = (float)(L_ - cnt) * sv;
  for (int a = 0; a < cnt; ++a) {
    const float* tr = tasp + (((b * 8 + h) * MAXA) + a) * DK_;
    float dd = 0.f;
    for (int e = 0; e < DK_; ++e) dd += tr[e] * kr[e];
    acc += tanhf(dd + bm);
  }
  s0[i] = sv;
  avg[i] = acc * (1.f / (float)L_);
}

__global__ void k_bar(const float* __restrict__ s0, const float* __restrict__ avg,
                      float* __restrict__ s0bar, float* __restrict__ avbar)
{
  int i = blockIdx.x * 256 + threadIdx.x;
  if (i >= B_ * L_) return;
  int m = i % L_, b = i / L_;
  float sa = 0.f, aa = 0.f;
  for (int h = 0; h < 8; ++h) { sa += s0[(b * 8 + h) * L_ + m]; aa += avg[(b * 8 + h) * L_ + m]; }
  s0bar[i] = sa * 0.125f;
  avbar[i] = aa * 0.125f;
}

__global__ __launch_bounds__(256) void k_adjag(
    const float* __restrict__ asp_mask, const float* __restrict__ adjr,
    const float* __restrict__ s0bar, const float* __restrict__ avbar,
    float* __restrict__ adjag, float* __restrict__ denag)
{
  int bl = blockIdx.x;
  int b = bl >> 9, l = bl & 511;
  bool rA = asp_mask[b * L_ + l] > 0.f;
  float avl = avbar[b * L_ + l];
  float lsum = 0.f;
  for (int q = 0; q < 2; ++q) {
    int m = threadIdx.x + q * 256;
    bool cA = asp_mask[b * L_ + m] > 0.f;
    float asv;
    if (cA && (!rA || m > l)) asv = avl;
    else if (rA)              asv = avbar[b * L_ + m];
    else                      asv = s0bar[b * L_ + m];
    float r = (asv > 0.9f) ? 1.f : __expf(0.8f * adjr[((long)b * L_ + l) * L_ + m]);
    float v = r * asv;
    adjag[((long)b * L_ + l) * L_ + m] = v;
    lsum += v;
  }
  __shared__ float red[256];
  red[threadIdx.x] = lsum;
  __syncthreads();
  for (int st = 128; st > 0; st >>= 1) {
    if (threadIdx.x < st) red[threadIdx.x] += red[threadIdx.x + st];
    __syncthreads();
  }
  if (threadIdx.x == 0) denag[bl] = red[0] + 1.f;
}

__global__ __launch_bounds__(256) void k_stats(
    const bf16* __restrict__ sc, const int* __restrict__ tok,
    float* __restrict__ mx, float* __restrict__ sm)
{
  int row = blockIdx.x * 4 + (threadIdx.x >> 6);
  int lane = threadIdx.x & 63;
  if (row >= B_ * 8 * L_) return;
  int b = row >> 12;
  const bf16* p = sc + (long)row * L_;
  const int* tkb = tok + b * L_;
  float v[8];
#pragma unroll
  for (int i = 0; i < 8; ++i) {
    int m = lane * 8 + i;
    float s = __bfloat162float(p[m]);
    v[i] = (tkb[m] != 0) ? s : -1e9f;
  }
  float mxl = v[0];
#pragma unroll
  for (int i = 1; i < 8; ++i) mxl = fmaxf(mxl, v[i]);
  for (int off = 32; off > 0; off >>= 1) mxl = fmaxf(mxl, __shfl_xor(mxl, off));
  float s = 0.f;
#pragma unroll
  for (int i = 0; i < 8; ++i) s += __expf(v[i] - mxl);
  for (int off = 32; off > 0; off >>= 1) s += __shfl_xor(s, off);
  if (lane == 0) { mx[row] = mxl; sm[row] = s; }
}

__global__ __launch_bounds__(256) void k_adjs(
    const bf16* __restrict__ sc, const int* __restrict__ tok,
    const float* __restrict__ mx, const float* __restrict__ sm,
    float* __restrict__ adjs, float* __restrict__ dens)
{
  int bl = blockIdx.x;
  int b = bl >> 9, l = bl & 511;
  float acc0 = 0.f, acc1 = 0.f;
  for (int h = 0; h < 8; ++h) {
    int row = (b * 8 + h) * L_ + l;
    float mxv = mx[row];
    float inv = 1.f / sm[row];
    const bf16* p = sc + (long)row * L_;
    {
      int m = threadIdx.x;
      float s = __bfloat162float(p[m]);
      s = (tok[b * L_ + m] != 0) ? s : -1e9f;
      acc0 += __expf(s - mxv) * inv;
    }
    {
      int m = threadIdx.x + 256;
      float s = __bfloat162float(p[m]);
      s = (tok[b * L_ + m] != 0) ? s : -1e9f;
      acc1 += __expf(s - mxv) * inv;
    }
  }
  float rmask = (tok[b * L_ + l] != 0) ? 1.f : 0.f;
  float lsum = 0.f;
  {
    int m = threadIdx.x;
    float v = acc0 * 0.125f;
    v = (m == l) ? 1.f : v;
    v *= rmask;
    adjs[(long)bl * L_ + m] = v;
    lsum += v;
  }
  {
    int m = threadIdx.x + 256;
    float v = acc1 * 0.125f;
    v = (m == l) ? 1.f : v;
    v *= rmask;
    adjs[(long)bl * L_ + m] = v;
    lsum += v;
  }
  __shared__ float red[256];
  red[threadIdx.x] = lsum;
  __syncthreads();
  for (int st = 128; st > 0; st >>= 1) {
    if (threadIdx.x < st) red[threadIdx.x] += red[threadIdx.x + st];
    __syncthreads();
  }
  if (threadIdx.x == 0) dens[bl] = red[0] + 1.f;
}

__global__ __launch_bounds__(256) void k_softmax(float* __restrict__ X)
{
  long row = blockIdx.x;
  float* p = X + row * L_;
  int tid = threadIdx.x;
  float a = p[tid], b = p[tid + 256];
  __shared__ float red[256];
  red[tid] = fmaxf(a, b);
  __syncthreads();
  for (int st = 128; st > 0; st >>= 1) {
    if (tid < st) red[tid] = fmaxf(red[tid], red[tid + st]);
    __syncthreads();
  }
  float mxv = red[0];
  __syncthreads();
  float ea = __expf(a - mxv), eb = __expf(b - mxv);
  red[tid] = ea + eb;
  __syncthreads();
  for (int st = 128; st > 0; st >>= 1) {
    if (tid < st) red[tid] += red[tid + st];
    __syncthreads();
  }
  float inv = 1.f / red[0];
  p[tid] = ea * inv;
  p[tid + 256] = eb * inv;
}

// ---------------------------------------------------------------- host side
static void gemm(hipStream_t st, bool nt,
                 const float* A, int lda, long sA1, long sA2,
                 const float* Bm, int ldb, long sB1, long sB2,
                 float* C, bf16* Cbf, int ldc, long sC1, long sC2,
                 const float* bias, const float* bias2, const float* rowdiv,
                 float alpha, int relu, int M, int N, int K, int nb1, int nb2)
{
  dim3 g((N + 63) / 64, (M + 63) / 64, nb1 * nb2);
  if (nt)
    k_mgemm<true><<<g, 256, 0, st>>>(A, lda, sA1, sA2, Bm, ldb, sB1, sB2, C, Cbf, ldc, sC1, sC2,
                                     bias, bias2, rowdiv, alpha, relu, M, N, K, nb2);
  else
    k_mgemm<false><<<g, 256, 0, st>>>(A, lda, sA1, sA2, Bm, ldb, sB1, sB2, C, Cbf, ldc, sC1, sC2,
                                      bias, bias2, rowdiv, alpha, relu, M, N, K, nb2);
}

extern "C" void kernel_launch(void* const* d_in, const int* in_sizes, int n_in,
                              void* d_out, int out_size, void* d_ws, size_t ws_size,
                              hipStream_t stream)
{
  const int*   tok     = (const int*)d_in[0];
  const int*   pos     = (const int*)d_in[1];
  const int*   post    = (const int*)d_in[2];
  const float* asp_mask= (const float*)d_in[3];
  const float* adjr    = (const float*)d_in[5];
  const float* emb_w   = (const float*)d_in[6];
  const float* pos_w   = (const float*)d_in[7];
  const float* post_w  = (const float*)d_in[8];
  const float* w_ih_f  = (const float*)d_in[9];
  const float* w_hh_f  = (const float*)d_in[10];
  const float* b_ih_f  = (const float*)d_in[11];
  const float* b_hh_f  = (const float*)d_in[12];
  const float* w_ih_b  = (const float*)d_in[13];
  const float* w_hh_b  = (const float*)d_in[14];
  const float* b_ih_b  = (const float*)d_in[15];
  const float* b_hh_b  = (const float*)d_in[16];
  const float* wq      = (const float*)d_in[17];
  const float* bq      = (const float*)d_in[18];
  const float* wk      = (const float*)d_in[19];
  const float* bk      = (const float*)d_in[20];
  const float* wd      = (const float*)d_in[21];
  const float* bd      = (const float*)d_in[22];
  const float* wm      = (const float*)d_in[23];
  const float* bias_m  = (const float*)d_in[24];
  const float* wa0     = (const float*)d_in[25];
  const float* ba0     = (const float*)d_in[26];
  const float* wa1     = (const float*)d_in[27];
  const float* ba1     = (const float*)d_in[28];
  const float* ws0     = (const float*)d_in[29];
  const float* bs0     = (const float*)d_in[30];
  const float* ws1     = (const float*)d_in[31];
  const float* bs1     = (const float*)d_in[32];
  const float* aff1    = (const float*)d_in[33];
  const float* aff2    = (const float*)d_in[34];
  float* out = (float*)d_out;
  float* W = (float*)d_ws;

  // ---- workspace layout (float units) ----
  size_t off = 0;
  auto alloc = [&](size_t n) { size_t o = off; off += (n + 63) & ~(size_t)63; return o; };
  size_t o_gcn   = alloc((size_t)8192 * DM_);
  size_t o_q     = alloc((size_t)8192 * DM_);
  size_t o_k     = alloc((size_t)8192 * DM_);
  size_t o_adjs  = alloc((size_t)B_ * L_ * L_);
  size_t o_dens  = alloc(8192);
  size_t o_adjag = alloc((size_t)B_ * L_ * L_);
  size_t o_denag = alloc(8192);
  size_t o_t0    = alloc(600);
  size_t o_apos  = alloc(B_ * MAXA);
  size_t o_acnt  = alloc(64);
  size_t o_aspd  = alloc(B_ * MAXA * DK_);
  size_t o_tasp  = alloc(B_ * 8 * MAXA * DK_);
  size_t o_s0    = alloc(B_ * 8 * L_);
  size_t o_avg   = alloc(B_ * 8 * L_);
  size_t o_s0bar = alloc(B_ * L_);
  size_t o_avbar = alloc(B_ * L_);
  size_t o_mx    = alloc(B_ * 8 * L_);
  size_t o_sm    = alloc(B_ * 8 * L_);
  size_t o_hg    = alloc(2 * 2 * 4800);     // u32 tagged-h
  size_t o_oag1  = alloc((size_t)8192 * 300);
  size_t o_os1   = alloc((size_t)8192 * 300);
  size_t o_big   = alloc(22609920);   // union region
  size_t o_embs = o_big;
  size_t o_pref = o_big + 2949120;
  size_t o_preb = o_pref + 9830400;
  size_t o_sc   = o_big;
  size_t o_tmp  = o_big;
  size_t o_gag  = o_big + 4915200;
  size_t o_gs   = o_gag + 2457600;
  size_t o_h1   = o_gs  + 2457600;
  size_t o_a1m  = o_h1  + 2457600;
  size_t o_a2m  = o_a1m + 4194304;

  if (ws_size < off * sizeof(float)) {
    (void)hipMemsetAsync(d_out, 0x7F, (size_t)out_size * sizeof(float), stream);
    return;
  }

  // 1) embeddings -> [t*16+b][360]
  k_embed<<<(L_ * B_ * 360 + 255) / 256, 256, 0, stream>>>(tok, pos, post, emb_w, pos_w, post_w, W + o_embs);

  // 2) pre-GEMMs: preT[j][t*16+b] = w_ih[j] . embs[(t,b)]  (biases added in k_lstm)
  gemm(stream, true, w_ih_f, 360, 0, 0, W + o_embs, 360, 0, 0,
       W + o_pref, nullptr, 8192, 0, 0, nullptr, nullptr, nullptr, 1.f, 0, 1200, 8192, 360, 1, 1);
  gemm(stream, true, w_ih_b, 360, 0, 0, W + o_embs, 360, 0, 0,
       W + o_preb, nullptr, 8192, 0, 0, nullptr, nullptr, nullptr, 1.f, 0, 1200, 8192, 360, 1, 1);

  // 3) BiLSTM: 76 sharded blocks, tagged-word sync
  k_lstm<<<2 * NCH, 256, 0, stream>>>(W + o_pref, W + o_preb, w_hh_f, w_hh_b,
                                      b_ih_f, b_hh_f, b_ih_b, b_hh_b,
                                      W + o_gcn, (unsigned*)(W + o_hg));

  // 4) q/k projections
  gemm(stream, true, W + o_gcn, DM_, 0, 0, wq, DM_, 0, 0,
       W + o_q, nullptr, DM_, 0, 0, bq, nullptr, nullptr, 1.f, 0, 8192, DM_, DM_, 1, 1);
  gemm(stream, true, W + o_gcn, DM_, 0, 0, wk, DM_, 0, 0,
       W + o_k, nullptr, DM_, 0, 0, bk, nullptr, nullptr, 1.f, 0, 8192, DM_, DM_, 1, 1);

  // 5) aspect structure
  k_asplist<<<1, 64, 0, stream>>>(asp_mask, (int*)(W + o_apos), (int*)(W + o_acnt));
  k_t0<<<(600 + 255) / 256, 256, 0, stream>>>(bd, wm, W + o_t0);
  k_aspd<<<(B_ * MAXA * DK_ + 255) / 256, 256, 0, stream>>>(W + o_gcn, asp_mask,
      (const int*)(W + o_apos), (const int*)(W + o_acnt), wd, bd, W + o_aspd);
  k_tasp<<<(B_ * 8 * MAXA * DK_ + 255) / 256, 256, 0, stream>>>(W + o_aspd,
      (const int*)(W + o_acnt), wm, W + o_tasp);
  k_avg<<<(B_ * 8 * L_ + 255) / 256, 256, 0, stream>>>(W + o_k, W + o_t0, W + o_tasp,
      (const int*)(W + o_acnt), bias_m, W + o_s0, W + o_avg);
  k_bar<<<(B_ * L_ + 255) / 256, 256, 0, stream>>>(W + o_s0, W + o_avg, W + o_s0bar, W + o_avbar);

  // 6) scores (bf16) -> stats -> adj_s ; adj_ag
  gemm(stream, true, W + o_q, DM_, (long)L_ * DM_, DK_, W + o_k, DM_, (long)L_ * DM_, DK_,
       nullptr, (bf16*)(W + o_sc), L_, (long)8 * L_ * L_, (long)L_ * L_,
       nullptr, nullptr, nullptr, 0.1154700538f, 0, L_, L_, DK_, B_, 8);
  k_stats<<<(B_ * 8 * L_) / 4, 256, 0, stream>>>((const bf16*)(W + o_sc), tok, W + o_mx, W + o_sm);
  k_adjs<<<B_ * L_, 256, 0, stream>>>((const bf16*)(W + o_sc), tok, W + o_mx, W + o_sm,
                                      W + o_adjs, W + o_dens);
  k_adjag<<<B_ * L_, 256, 0, stream>>>(asp_mask, adjr, W + o_s0bar, W + o_avbar,
                                       W + o_adjag, W + o_denag);

  // 7) two GCN layers
  const float* waL[2] = {wa0, wa1};
  const float* baL[2] = {ba0, ba1};
  const float* wsL[2] = {ws0, ws1};
  const float* bsL[2] = {bs0, bs1};
  const float* inAg = W + o_gcn;
  const float* inS  = W + o_gcn;
  int D = DM_;
  for (int layer = 0; layer < 2; ++layer) {
    gemm(stream, false, W + o_adjag, L_, (long)L_ * L_, 0, inAg, D, (long)L_ * D, 0,
         W + o_tmp, nullptr, D, (long)L_ * D, 0, nullptr, nullptr, nullptr, 1.f, 0, L_, D, L_, B_, 1);
    gemm(stream, true, W + o_tmp, D, 0, 0, waL[layer], D, 0, 0,
         W + o_gag, nullptr, 300, 0, 0, baL[layer], nullptr, W + o_denag, 1.f, 1, 8192, 300, D, 1, 1);
    gemm(stream, false, W + o_adjs, L_, (long)L_ * L_, 0, inS, D, (long)L_ * D, 0,
         W + o_tmp, nullptr, D, (long)L_ * D, 0, nullptr, nullptr, nullptr, 1.f, 0, L_, D, L_, B_, 1);
    gemm(stream, true, W + o_tmp, D, 0, 0, wsL[layer], D, 0, 0,
         W + o_gs, nullptr, 300, 0, 0, bsL[layer], nullptr, W + o_dens, 1.f, 1, 8192, 300, D, 1, 1);
    gemm(stream, false, W + o_gag, 300, 0, 0, aff1, 300, 0, 0,
         W + o_h1, nullptr, 300, 0, 0, nullptr, nullptr, nullptr, 1.f, 0, 8192, 300, 300, 1, 1);
    gemm(stream, true, W + o_h1, 300, (long)L_ * 300, 0, W + o_gs, 300, (long)L_ * 300, 0,
         W + o_a1m, nullptr, L_, (long)L_ * L_, 0, nullptr, nullptr, nullptr, 1.f, 0, L_, L_, 300, B_, 1);
    k_softmax<<<B_ * L_, 256, 0, stream>>>(W + o_a1m);
    gemm(stream, false, W + o_gs, 300, 0, 0, aff2, 300, 0, 0,
         W + o_h1, nullptr, 300, 0, 0, nullptr, nullptr, nullptr, 1.f, 0, 8192, 300, 300, 1, 1);
    gemm(stream, true, W + o_h1, 300, (long)L_ * 300, 0, W + o_gag, 300, (long)L_ * 300, 0,
         W + o_a2m, nullptr, L_, (long)L_ * L_, 0, nullptr, nullptr, nullptr, 1.f, 0, L_, L_, 300, B_, 1);
    k_softmax<<<B_ * L_, 256, 0, stream>>>(W + o_a2m);
    float* dstAg; float* dstS; int ldcO; long sCO;
    if (layer == 0) { dstAg = W + o_oag1; dstS = W + o_os1; ldcO = 300; sCO = (long)L_ * 300; }
    else            { dstAg = out;        dstS = out + 300; ldcO = 600; sCO = (long)L_ * 600; }
    gemm(stream, false, W + o_a1m, L_, (long)L_ * L_, 0, W + o_gs, 300, (long)L_ * 300, 0,
         dstAg, nullptr, ldcO, sCO, 0, nullptr, nullptr, nullptr, 1.f, 0, L_, 300, L_, B_, 1);
    gemm(stream, false, W + o_a2m, L_, (long)L_ * L_, 0, W + o_gag, 300, (long)L_ * 300, 0,
         dstS, nullptr, ldcO, sCO, 0, nullptr, nullptr, nullptr, 1.f, 0, L_, 300, L_, B_, 1);
    inAg = W + o_oag1;
    inS  = W + o_os1;
    D = 300;
  }
}

// Round 9
// 3423.633 us; speedup vs baseline: 2.8560x; 1.0219x over previous
//
#include <hip/hip_runtime.h>
#include <hip/hip_bf16.h>

typedef __hip_bfloat16 bf16;
typedef __attribute__((ext_vector_type(4))) short short4v;
typedef __attribute__((ext_vector_type(8))) short short8v;
typedef __attribute__((ext_vector_type(4))) float f32x4;

#define B_   16
#define L_   512
#define HR   300
#define DM_  600
#define DK_  75
#define MAXA 8
#define NCH  38            // u-chunks per dir (37*8 + 4)

// ---------------------------------------------------------------- embed
// embs layout: [seq = t*16 + b][360]
__global__ __launch_bounds__(256) void k_embed(
    const int* __restrict__ tok, const int* __restrict__ pos, const int* __restrict__ post,
    const float* __restrict__ emb_w, const float* __restrict__ pos_w, const float* __restrict__ post_w,
    float* __restrict__ embs)
{
  int idx = blockIdx.x * 256 + threadIdx.x;
  if (idx >= L_ * B_ * 360) return;
  int d = idx % 360;
  int seq = idx / 360;
  int b = seq & 15, t = seq >> 4;
  int si = b * L_ + t;
  float v;
  if (d < 300)       v = emb_w[(long)tok[si] * 300 + d];
  else if (d < 330)  v = pos_w[pos[si] * 30 + (d - 300)];
  else               v = post_w[post[si] * 30 + (d - 330)];
  embs[idx] = v;
}

// ---------------------------------------------------------------- weight staging (one launch)
// dst layout: wqk[720000] | bqk[1200] | wih[864000] | aff[180000]
__global__ __launch_bounds__(256) void k_stage(
    const float* __restrict__ wq, const float* __restrict__ wk,
    const float* __restrict__ bq, const float* __restrict__ bk,
    const float* __restrict__ wihf, const float* __restrict__ wihb,
    const float* __restrict__ aff1, const float* __restrict__ aff2,
    float* __restrict__ wqk, float* __restrict__ bqk,
    float* __restrict__ wih, float* __restrict__ aff)
{
  int i = blockIdx.x * 256 + threadIdx.x;
  if (i < 360000) wqk[i] = wq[i];
  else if (i < 720000) wqk[i] = wk[i - 360000];
  else if (i < 720600) bqk[i - 720000] = bq[i - 720000];
  else if (i < 721200) bqk[i - 720000] = bk[i - 720600];
  else if (i < 1153200) wih[i - 721200] = wihf[i - 721200];
  else if (i < 1585200) wih[i - 721200] = wihb[i - 1153200];
  else if (i < 1675200) aff[i - 1585200] = aff1[i - 1585200];
  else if (i < 1765200) aff[i - 1585200] = aff2[i - 1675200];
}

// ---------------------------------------------------------------- MFMA GEMM (bf16x3 split), 128x64 tile
__device__ inline short2 splitf(float x) {
  bf16 h = __float2bfloat16(x);
  float r = x - __bfloat162float(h);
  bf16 l2 = __float2bfloat16(r);
  short2 out;
  out.x = *reinterpret_cast<short*>(&h);
  out.y = *reinterpret_cast<short*>(&l2);
  return out;
}

__device__ inline short8v ld_frag(const short* p) {
  short4v a = *reinterpret_cast<const short4v*>(p);
  short4v b = *reinterpret_cast<const short4v*>(p + 16);
  short8v r;
  r[0]=a[0]; r[1]=a[1]; r[2]=a[2]; r[3]=a[3];
  r[4]=b[0]; r[5]=b[1]; r[6]=b[2]; r[7]=b[3];
  return r;
}

#define LDA_ 36   // row stride in shorts (32 + 4 pad)

template<bool NT>
__global__ __launch_bounds__(256) void k_mgemm(
    const float* __restrict__ A, int lda, long sA1, long sA2,
    const float* __restrict__ Bm, int ldb, long sB1, long sB2,
    float* __restrict__ C, bf16* __restrict__ Cbf, int ldc, long sC1, long sC2,
    const float* __restrict__ bias, long sBias,
    const float* __restrict__ rowdiv,
    float alpha, int relu, int M, int N, int K, int nb2)
{
  __shared__ short Ah[128 * LDA_], Al[128 * LDA_], Bh[64 * LDA_], Bl[64 * LDA_];
  const int tid = threadIdx.x;
  const int w = tid >> 6, l = tid & 63;
  const int z = blockIdx.z;
  const int b1 = z / nb2, b2 = z - b1 * nb2;
  const float* Ab = A + b1 * sA1 + b2 * sA2;
  const float* Bb = Bm + b1 * sB1 + b2 * sB2;
  const int row0 = blockIdx.y * 128, col0 = blockIdx.x * 64;

  f32x4 acc[2][4];
#pragma unroll
  for (int f = 0; f < 2; ++f)
#pragma unroll
    for (int c = 0; c < 4; ++c) acc[f][c] = (f32x4){0.f, 0.f, 0.f, 0.f};

  const int lrow = l & 15, lk = (l >> 4) * 4;

  for (int k0 = 0; k0 < K; k0 += 32) {
    // ---- stage A: 128 rows x 32 k (1024 float4-slots) ----
#pragma unroll
    for (int j = 0; j < 4; ++j) {
      int slot = j * 256 + tid;
      int r = slot >> 3, kq = slot & 7;
      int gr = row0 + r, gk = k0 + kq * 4;
      float v[4] = {0.f, 0.f, 0.f, 0.f};
      if (gr < M) {
        if (gk + 3 < K) {
          float4 t = *reinterpret_cast<const float4*>(Ab + (long)gr * lda + gk);
          v[0] = t.x; v[1] = t.y; v[2] = t.z; v[3] = t.w;
        } else {
#pragma unroll
          for (int q = 0; q < 4; ++q) if (gk + q < K) v[q] = Ab[(long)gr * lda + gk + q];
        }
      }
      short4v hv, lv;
#pragma unroll
      for (int q = 0; q < 4; ++q) {
        short2 t2 = splitf(v[q]);
        hv[q] = t2.x; lv[q] = t2.y;
      }
      *reinterpret_cast<short4v*>(&Ah[r * LDA_ + kq * 4]) = hv;
      *reinterpret_cast<short4v*>(&Al[r * LDA_ + kq * 4]) = lv;
    }
    // ---- stage B: 64 x 32 ----
    if (NT) {
#pragma unroll
      for (int j = 0; j < 2; ++j) {
        int slot = j * 256 + tid;
        int r = slot >> 3, kq = slot & 7;
        int gc = col0 + r, gk = k0 + kq * 4;
        float v[4] = {0.f, 0.f, 0.f, 0.f};
        if (gc < N) {
          if (gk + 3 < K) {
            float4 t = *reinterpret_cast<const float4*>(Bb + (long)gc * ldb + gk);
            v[0] = t.x; v[1] = t.y; v[2] = t.z; v[3] = t.w;
          } else {
#pragma unroll
            for (int q = 0; q < 4; ++q) if (gk + q < K) v[q] = Bb[(long)gc * ldb + gk + q];
          }
        }
        short4v hv, lv;
#pragma unroll
        for (int q = 0; q < 4; ++q) {
          short2 t2 = splitf(v[q]);
          hv[q] = t2.x; lv[q] = t2.y;
        }
        *reinterpret_cast<short4v*>(&Bh[r * LDA_ + kq * 4]) = hv;
        *reinterpret_cast<short4v*>(&Bl[r * LDA_ + kq * 4]) = lv;
      }
    } else {
#pragma unroll
      for (int j = 0; j < 2; ++j) {
        int slot = j * 256 + tid;
        int kk = slot >> 4, nq = slot & 15;
        int gk = k0 + kk, gn = col0 + nq * 4;
        float v[4] = {0.f, 0.f, 0.f, 0.f};
        if (gk < K) {
          if (gn + 3 < N) {
            float4 t = *reinterpret_cast<const float4*>(Bb + (long)gk * ldb + gn);
            v[0] = t.x; v[1] = t.y; v[2] = t.z; v[3] = t.w;
          } else {
#pragma unroll
            for (int q = 0; q < 4; ++q) if (gn + q < N) v[q] = Bb[(long)gk * ldb + gn + q];
          }
        }
#pragma unroll
        for (int q = 0; q < 4; ++q) {
          short2 t2 = splitf(v[q]);
          Bh[(nq * 4 + q) * LDA_ + kk] = t2.x;
          Bl[(nq * 4 + q) * LDA_ + kk] = t2.y;
        }
      }
    }
    __syncthreads();

    // ---- compute: wave w owns rows w*32..w*32+31 (2 frags) ----
    short8v ah[2], al[2];
#pragma unroll
    for (int f = 0; f < 2; ++f) {
      int ar = w * 32 + f * 16 + lrow;
      ah[f] = ld_frag(&Ah[ar * LDA_ + lk]);
      al[f] = ld_frag(&Al[ar * LDA_ + lk]);
    }
#pragma unroll
    for (int c = 0; c < 4; ++c) {
      short8v bh = ld_frag(&Bh[(c * 16 + lrow) * LDA_ + lk]);
      short8v bl = ld_frag(&Bl[(c * 16 + lrow) * LDA_ + lk]);
#pragma unroll
      for (int f = 0; f < 2; ++f) {
        acc[f][c] = __builtin_amdgcn_mfma_f32_16x16x32_bf16(ah[f], bh, acc[f][c], 0, 0, 0);
        acc[f][c] = __builtin_amdgcn_mfma_f32_16x16x32_bf16(ah[f], bl, acc[f][c], 0, 0, 0);
        acc[f][c] = __builtin_amdgcn_mfma_f32_16x16x32_bf16(al[f], bh, acc[f][c], 0, 0, 0);
      }
    }
    __syncthreads();
  }

  float* Cb = C ? C + b1 * sC1 + b2 * sC2 : (float*)0;
  bf16*  Cf = Cbf ? Cbf + b1 * sC1 + b2 * sC2 : (bf16*)0;
#pragma unroll
  for (int f = 0; f < 2; ++f)
#pragma unroll
  for (int c = 0; c < 4; ++c) {
    int cc = col0 + c * 16 + lrow;
    if (cc >= N) continue;
#pragma unroll
    for (int reg = 0; reg < 4; ++reg) {
      int r = row0 + w * 32 + f * 16 + (l >> 4) * 4 + reg;
      if (r >= M) continue;
      float v = acc[f][c][reg] * alpha;
      if (bias) v += bias[b1 * sBias + cc];
      if (rowdiv) v /= rowdiv[(long)z * M + r];
      if (relu) v = fmaxf(v, 0.f);
      if (Cf) Cf[(long)r * ldc + cc] = __float2bfloat16(v);
      else    Cb[(long)r * ldc + cc] = v;
    }
  }
}

// ---------------------------------------------------------------- BiLSTM (tagged-word sync)
__global__ __launch_bounds__(256, 1) void k_lstm(
    const float* __restrict__ preT_f, const float* __restrict__ preT_b,
    const float* __restrict__ whh_f, const float* __restrict__ whh_b,
    const float* __restrict__ bih_f, const float* __restrict__ bhh_f,
    const float* __restrict__ bih_b, const float* __restrict__ bhh_b,
    float* __restrict__ gcn, unsigned* __restrict__ hg)
{
  const int tid = threadIdx.x;
  const int dir = blockIdx.x / NCH;
  const int blk = blockIdx.x - dir * NCH;
  const int u0 = blk * 8;
  const int uc = min(8, HR - u0);
  const float* pre = dir ? preT_b : preT_f;
  const float* whh = dir ? whh_b : whh_f;
  const float* bih = dir ? bih_b : bih_f;
  const float* bhh = dir ? bhh_b : bhh_f;
  unsigned* hgd = hg + dir * 4800;              // + buf*9600

  __shared__ float4 h5[1200];                   // h[k][b] linear: write-conflict-free, reads broadcast
  __shared__ float part[32 * 545 + 64];
  __shared__ float g_lds[512];
  float* h5f = reinterpret_cast<float*>(h5);

  const int kc = tid >> 3;
  const int rq = tid & 7;
  const int kl = (kc < 12) ? 10 : 9;
  const int k0 = kc * 9 + min(kc, 12);

  float wreg[4][10];
#pragma unroll
  for (int i = 0; i < 4; ++i) {
    int lr = rq * 4 + i;
    int gate = lr >> 3, unit = lr & 7;
    bool valid = unit < uc;
    int growc = gate * HR + u0 + min(unit, uc - 1);
#pragma unroll
    for (int kk = 0; kk < 10; ++kk) {
      int k = min(k0 + kk, 299);
      float wv = whh[(long)growc * HR + k];
      wreg[i][kk] = (valid && kk < kl) ? wv : 0.f;
    }
  }

  const int o0 = tid * 2;
  const int lr0 = o0 >> 4;
  const int b0 = o0 & 15;
  const int gate0 = lr0 >> 3, unit0 = lr0 & 7;
  const int grow0 = gate0 * HR + u0 + min(unit0, uc - 1);
  const float breg = bih[grow0] + bhh[grow0];
  const float* prebase = pre + (long)grow0 * 8192;

  const int au = tid >> 4, ab = tid & 15;
  float c_reg = 0.f;

  const int own_lo = u0 * 16, own_hi = (u0 + uc) * 16;

#pragma unroll 1
  for (int s = 0; s < L_; ++s) {
    const int tf = dir ? (L_ - 1 - s) : s;

    float p0 = prebase[tf * 16 + b0];
    float p1 = prebase[tf * 16 + b0 + 1];

    if (s > 0) {
      unsigned* srcb = hgd + (s & 1) * 9600;
      const unsigned tag = (unsigned)s;
      unsigned vals[19];
      int idxs[19];
#pragma unroll
      for (int j = 0; j < 19; ++j) {
        int idx = tid + j * 256;
        bool act = (idx < 4800) && (idx < own_lo || idx >= own_hi);
        idxs[j] = act ? idx : -1;
        vals[j] = act ? __hip_atomic_load(&srcb[idx], __ATOMIC_RELAXED, __HIP_MEMORY_SCOPE_AGENT)
                      : (tag << 16);
      }
      for (;;) {
        bool ok = true;
#pragma unroll
        for (int j = 0; j < 19; ++j)
          if ((vals[j] >> 16) != tag) ok = false;
        if (ok) break;
#pragma unroll
        for (int j = 0; j < 19; ++j)
          if ((vals[j] >> 16) != tag)
            vals[j] = __hip_atomic_load(&srcb[idxs[j]], __ATOMIC_RELAXED, __HIP_MEMORY_SCOPE_AGENT);
      }
#pragma unroll
      for (int j = 0; j < 19; ++j) {
        int idx = idxs[j];
        if (idx >= 0) {
          unsigned short hb = (unsigned short)(vals[j] & 0xffffu);
          bf16 hbf = *reinterpret_cast<bf16*>(&hb);
          h5f[idx] = __bfloat162float(hbf);
        }
      }
    }
    __syncthreads();

    if (s > 0) {
      float4 acc[4][4];
#pragma unroll
      for (int i = 0; i < 4; ++i)
#pragma unroll
        for (int q = 0; q < 4; ++q) acc[i][q] = make_float4(0.f, 0.f, 0.f, 0.f);
#pragma unroll
      for (int kk = 0; kk < 10; ++kk) {
        if (kk < kl) {
          int k = k0 + kk;
          float4 hb0 = h5[k * 4 + 0];
          float4 hb1 = h5[k * 4 + 1];
          float4 hb2 = h5[k * 4 + 2];
          float4 hb3 = h5[k * 4 + 3];
#pragma unroll
          for (int i = 0; i < 4; ++i) {
            float w = wreg[i][kk];
            acc[i][0].x = fmaf(w, hb0.x, acc[i][0].x); acc[i][0].y = fmaf(w, hb0.y, acc[i][0].y);
            acc[i][0].z = fmaf(w, hb0.z, acc[i][0].z); acc[i][0].w = fmaf(w, hb0.w, acc[i][0].w);
            acc[i][1].x = fmaf(w, hb1.x, acc[i][1].x); acc[i][1].y = fmaf(w, hb1.y, acc[i][1].y);
            acc[i][1].z = fmaf(w, hb1.z, acc[i][1].z); acc[i][1].w = fmaf(w, hb1.w, acc[i][1].w);
            acc[i][2].x = fmaf(w, hb2.x, acc[i][2].x); acc[i][2].y = fmaf(w, hb2.y, acc[i][2].y);
            acc[i][2].z = fmaf(w, hb2.z, acc[i][2].z); acc[i][2].w = fmaf(w, hb2.w, acc[i][2].w);
            acc[i][3].x = fmaf(w, hb3.x, acc[i][3].x); acc[i][3].y = fmaf(w, hb3.y, acc[i][3].y);
            acc[i][3].z = fmaf(w, hb3.z, acc[i][3].z); acc[i][3].w = fmaf(w, hb3.w, acc[i][3].w);
          }
        }
      }
#pragma unroll
      for (int i = 0; i < 4; ++i) {
        int lr = rq * 4 + i;
        float* pb = part + kc * 545 + lr * 17;
#pragma unroll
        for (int q = 0; q < 4; ++q) {
          pb[q * 4 + 0] = acc[i][q].x; pb[q * 4 + 1] = acc[i][q].y;
          pb[q * 4 + 2] = acc[i][q].z; pb[q * 4 + 3] = acc[i][q].w;
        }
      }
    }
    __syncthreads();

    float g0 = p0 + breg, g1 = p1 + breg;
    if (s > 0) {
      const float* pb = part + lr0 * 17 + b0;
#pragma unroll
      for (int q = 0; q < 32; ++q) { g0 += pb[q * 545]; g1 += pb[q * 545 + 1]; }
    }
    g_lds[o0] = g0; g_lds[o0 + 1] = g1;
    __syncthreads();

    if (tid < 128 && au < uc) {
      float gi = g_lds[(0 * 8 + au) * 16 + ab];
      float gf = g_lds[(1 * 8 + au) * 16 + ab];
      float gg = g_lds[(2 * 8 + au) * 16 + ab];
      float go = g_lds[(3 * 8 + au) * 16 + ab];
      float si = 1.f / (1.f + __expf(-gi));
      float sf = 1.f / (1.f + __expf(-gf));
      float so = 1.f / (1.f + __expf(-go));
      float tg = tanhf(gg);
      c_reg = sf * c_reg + si * tg;
      float h = so * tanhf(c_reg);
      h5f[(u0 + au) * 16 + ab] = h;
      bf16 hbf = __float2bfloat16(h);
      unsigned bits = *reinterpret_cast<unsigned short*>(&hbf);
      unsigned val = ((unsigned)(s + 1) << 16) | bits;
      __hip_atomic_store(&hgd[((s + 1) & 1) * 9600 + (u0 + au) * 16 + ab], val,
                         __ATOMIC_RELAXED, __HIP_MEMORY_SCOPE_AGENT);
      gcn[((long)ab * L_ + tf) * DM_ + dir * HR + u0 + au] = h;
    }
  }
}

// ---------------------------------------------------------------- small aspect kernels
__global__ void k_asplist(const float* __restrict__ asp_mask, int* __restrict__ apos, int* __restrict__ acnt)
{
  int b = threadIdx.x;
  if (b >= B_) return;
  int c = 0;
  for (int l = 0; l < L_; ++l)
    if (asp_mask[b * L_ + l] > 0.f) { if (c < MAXA) apos[b * MAXA + c] = l; ++c; }
  acnt[b] = (c < MAXA) ? c : MAXA;
}

__global__ void k_t0(const float* __restrict__ bd, const float* __restrict__ wm, float* __restrict__ t0)
{
  int i = blockIdx.x * 256 + threadIdx.x;
  if (i >= 8 * DK_) return;
  int h = i / DK_, e = i % DK_;
  float s = 0.f;
  for (int d = 0; d < DK_; ++d) s += bd[d] * wm[(h * DK_ + d) * DK_ + e];
  t0[i] = s;
}

__global__ void k_aspd(const float* __restrict__ gcn, const float* __restrict__ asp_mask,
                       const int* __restrict__ apos, const int* __restrict__ acnt,
                       const float* __restrict__ wd, const float* __restrict__ bd, float* __restrict__ aspd)
{
  int i = blockIdx.x * 256 + threadIdx.x;
  if (i >= B_ * MAXA * DK_) return;
  int d = i % DK_;
  int ba = i / DK_;
  int a = ba % MAXA, b = ba / MAXA;
  if (a >= acnt[b]) { aspd[i] = 0.f; return; }
  int p = apos[b * MAXA + a];
  float mv = asp_mask[b * L_ + p];
  const float* row = gcn + ((long)b * L_ + p) * DM_;
  float s = 0.f;
  for (int k = 0; k < DM_; ++k) s += row[k] * wd[d * DM_ + k];
  aspd[i] = s * mv + bd[d];
}

__global__ void k_tasp(const float* __restrict__ aspd, const int* __restrict__ acnt,
                       const float* __restrict__ wm, float* __restrict__ tasp)
{
  int i = blockIdx.x * 256 + threadIdx.x;
  if (i >= B_ * 8 * MAXA * DK_) return;
  int e = i % DK_;
  int t3 = i / DK_;
  int a = t3 % MAXA;
  int t4 = t3 / MAXA;
  int h = t4 % 8, b = t4 / 8;
  if (a >= acnt[b]) { tasp[i] = 0.f; return; }
  const float* ar = aspd + (b * MAXA + a) * DK_;
  float s = 0.f;
  for (int d = 0; d < DK_; ++d) s += ar[d] * wm[(h * DK_ + d) * DK_ + e];
  tasp[i] = s;
}

__global__ void k_avg(const float* __restrict__ k_lin, const float* __restrict__ t0,
                      const float* __restrict__ tasp, const int* __restrict__ acnt,
                      const float* __restrict__ bias_m, float* __restrict__ s0, float* __restrict__ avg)
{
  int i = blockIdx.x * 256 + threadIdx.x;
  if (i >= B_ * 8 * L_) return;
  int m = i % L_;
  int bh = i / L_;
  int h = bh % 8, b = bh / 8;
  const float* kr = k_lin + ((long)b * L_ + m) * DM_ + h * DK_;
  float bm = bias_m[0];
  const float* t0r = t0 + h * DK_;
  float d0 = 0.f;
  for (int e = 0; e < DK_; ++e) d0 += t0r[e] * kr[e];
  float sv = tanhf(d0 + bm);
  int cnt = acnt[b];
  float acc = (float)(L_ - cnt) * sv;
  for (int a = 0; a < cnt; ++a) {
    const float* tr = tasp + (((b * 8 + h) * MAXA) + a) * DK_;
    float dd = 0.f;
    for (int e = 0; e < DK_; ++e) dd += tr[e] * kr[e];
    acc += tanhf(dd + bm);
  }
  s0[i] = sv;
  avg[i] = acc * (1.f / (float)L_);
}

__global__ void k_bar(const float* __restrict__ s0, const float* __restrict__ avg,
                      float* __restrict__ s0bar, float* __restrict__ avbar)
{
  int i = blockIdx.x * 256 + threadIdx.x;
  if (i >= B_ * L_) return;
  int m = i % L_, b = i / L_;
  float sa = 0.f, aa = 0.f;
  for (int h = 0; h < 8; ++h) { sa += s0[(b * 8 + h) * L_ + m]; aa += avg[(b * 8 + h) * L_ + m]; }
  s0bar[i] = sa * 0.125f;
  avbar[i] = aa * 0.125f;
}

__global__ __launch_bounds__(256) void k_adjag(
    const float* __restrict__ asp_mask, const float* __restrict__ adjr,
    const float* __restrict__ s0bar, const float* __restrict__ avbar,
    float* __restrict__ adjag, float* __restrict__ denag)
{
  int bl = blockIdx.x;
  int b = bl >> 9, l = bl & 511;
  bool rA = asp_mask[b * L_ + l] > 0.f;
  float avl = avbar[b * L_ + l];
  float lsum = 0.f;
  for (int q = 0; q < 2; ++q) {
    int m = threadIdx.x + q * 256;
    bool cA = asp_mask[b * L_ + m] > 0.f;
    float asv;
    if (cA && (!rA || m > l)) asv = avl;
    else if (rA)              asv = avbar[b * L_ + m];
    else                      asv = s0bar[b * L_ + m];
    float r = (asv > 0.9f) ? 1.f : __expf(0.8f * adjr[((long)b * L_ + l) * L_ + m]);
    float v = r * asv;
    adjag[((long)b * L_ + l) * L_ + m] = v;
    lsum += v;
  }
  __shared__ float red[256];
  red[threadIdx.x] = lsum;
  __syncthreads();
  for (int st = 128; st > 0; st >>= 1) {
    if (threadIdx.x < st) red[threadIdx.x] += red[threadIdx.x + st];
    __syncthreads();
  }
  if (threadIdx.x == 0) denag[bl] = red[0] + 1.f;
}

// fused stats + head-mean softmax + diag/mask + denom; one block per (b,l)
__global__ __launch_bounds__(256) void k_adjs2(
    const bf16* __restrict__ sc, const int* __restrict__ tok,
    float* __restrict__ adjs, float* __restrict__ dens)
{
  int bl = blockIdx.x;
  int b = bl >> 9, l = bl & 511;
  int tid = threadIdx.x;
  __shared__ float srow[8][512];
  __shared__ float stats[16];    // mx[0..7], inv[8..15]
  __shared__ float red[256];

  int t0v = tok[b * L_ + tid], t1v = tok[b * L_ + tid + 256];
#pragma unroll
  for (int h = 0; h < 8; ++h) {
    const bf16* p = sc + ((long)((b * 8 + h) * L_) + l) * L_;
    float v0 = __bfloat162float(p[tid]);
    float v1 = __bfloat162float(p[tid + 256]);
    srow[h][tid]       = (t0v != 0) ? v0 : -1e9f;
    srow[h][tid + 256] = (t1v != 0) ? v1 : -1e9f;
  }
  __syncthreads();

  int wv = tid >> 6, lane = tid & 63;
#pragma unroll
  for (int hh = 0; hh < 2; ++hh) {
    int h = wv * 2 + hh;
    float vv[8];
#pragma unroll
    for (int i = 0; i < 8; ++i) vv[i] = srow[h][lane + i * 64];
    float m = vv[0];
#pragma unroll
    for (int i = 1; i < 8; ++i) m = fmaxf(m, vv[i]);
    for (int off = 32; off > 0; off >>= 1) m = fmaxf(m, __shfl_xor(m, off));
    float s = 0.f;
#pragma unroll
    for (int i = 0; i < 8; ++i) s += __expf(vv[i] - m);
    for (int off = 32; off > 0; off >>= 1) s += __shfl_xor(s, off);
    if (lane == 0) { stats[h] = m; stats[8 + h] = 1.f / s; }
  }
  __syncthreads();

  float acc0 = 0.f, acc1 = 0.f;
#pragma unroll
  for (int h = 0; h < 8; ++h) {
    float m = stats[h], inv = stats[8 + h];
    acc0 += __expf(srow[h][tid] - m) * inv;
    acc1 += __expf(srow[h][tid + 256] - m) * inv;
  }
  float rmask = (tok[b * L_ + l] != 0) ? 1.f : 0.f;
  float lsum = 0.f;
  {
    int m = tid;
    float v = acc0 * 0.125f;
    v = (m == l) ? 1.f : v;
    v *= rmask;
    adjs[(long)bl * L_ + m] = v;
    lsum += v;
  }
  {
    int m = tid + 256;
    float v = acc1 * 0.125f;
    v = (m == l) ? 1.f : v;
    v *= rmask;
    adjs[(long)bl * L_ + m] = v;
    lsum += v;
  }
  red[tid] = lsum;
  __syncthreads();
  for (int st = 128; st > 0; st >>= 1) {
    if (tid < st) red[tid] += red[tid + st];
    __syncthreads();
  }
  if (tid == 0) dens[bl] = red[0] + 1.f;
}

__global__ __launch_bounds__(256) void k_softmax(float* __restrict__ X)
{
  long row = blockIdx.x;
  float* p = X + row * L_;
  int tid = threadIdx.x;
  float a = p[tid], b = p[tid + 256];
  __shared__ float red[256];
  red[tid] = fmaxf(a, b);
  __syncthreads();
  for (int st = 128; st > 0; st >>= 1) {
    if (tid < st) red[tid] = fmaxf(red[tid], red[tid + st]);
    __syncthreads();
  }
  float mxv = red[0];
  __syncthreads();
  float ea = __expf(a - mxv), eb = __expf(b - mxv);
  red[tid] = ea + eb;
  __syncthreads();
  for (int st = 128; st > 0; st >>= 1) {
    if (tid < st) red[tid] += red[tid + st];
    __syncthreads();
  }
  float inv = 1.f / red[0];
  p[tid] = ea * inv;
  p[tid + 256] = eb * inv;
}

// ---------------------------------------------------------------- host side
static void gemm(hipStream_t st, bool nt,
                 const float* A, int lda, long sA1, long sA2,
                 const float* Bm, int ldb, long sB1, long sB2,
                 float* C, bf16* Cbf, int ldc, long sC1, long sC2,
                 const float* bias, long sBias, const float* rowdiv,
                 float alpha, int relu, int M, int N, int K, int nb1, int nb2)
{
  dim3 g((N + 63) / 64, (M + 127) / 128, nb1 * nb2);
  if (nt)
    k_mgemm<true><<<g, 256, 0, st>>>(A, lda, sA1, sA2, Bm, ldb, sB1, sB2, C, Cbf, ldc, sC1, sC2,
                                     bias, sBias, rowdiv, alpha, relu, M, N, K, nb2);
  else
    k_mgemm<false><<<g, 256, 0, st>>>(A, lda, sA1, sA2, Bm, ldb, sB1, sB2, C, Cbf, ldc, sC1, sC2,
                                      bias, sBias, rowdiv, alpha, relu, M, N, K, nb2);
}

extern "C" void kernel_launch(void* const* d_in, const int* in_sizes, int n_in,
                              void* d_out, int out_size, void* d_ws, size_t ws_size,
                              hipStream_t stream)
{
  const int*   tok     = (const int*)d_in[0];
  const int*   pos     = (const int*)d_in[1];
  const int*   post    = (const int*)d_in[2];
  const float* asp_mask= (const float*)d_in[3];
  const float* adjr    = (const float*)d_in[5];
  const float* emb_w   = (const float*)d_in[6];
  const float* pos_w   = (const float*)d_in[7];
  const float* post_w  = (const float*)d_in[8];
  const float* w_ih_f  = (const float*)d_in[9];
  const float* w_hh_f  = (const float*)d_in[10];
  const float* b_ih_f  = (const float*)d_in[11];
  const float* b_hh_f  = (const float*)d_in[12];
  const float* w_ih_b  = (const float*)d_in[13];
  const float* w_hh_b  = (const float*)d_in[14];
  const float* b_ih_b  = (const float*)d_in[15];
  const float* b_hh_b  = (const float*)d_in[16];
  const float* wq      = (const float*)d_in[17];
  const float* bq      = (const float*)d_in[18];
  const float* wk      = (const float*)d_in[19];
  const float* bk      = (const float*)d_in[20];
  const float* wd      = (const float*)d_in[21];
  const float* bd      = (const float*)d_in[22];
  const float* wm      = (const float*)d_in[23];
  const float* bias_m  = (const float*)d_in[24];
  const float* wa0     = (const float*)d_in[25];
  const float* ba0     = (const float*)d_in[26];
  const float* wa1     = (const float*)d_in[27];
  const float* ba1     = (const float*)d_in[28];
  const float* ws0     = (const float*)d_in[29];
  const float* bs0     = (const float*)d_in[30];
  const float* ws1     = (const float*)d_in[31];
  const float* bs1     = (const float*)d_in[32];
  const float* aff1    = (const float*)d_in[33];
  const float* aff2    = (const float*)d_in[34];
  float* out = (float*)d_out;
  float* W = (float*)d_ws;

  // ---- workspace layout (float units) ----
  size_t off = 0;
  auto alloc = [&](size_t n) { size_t o = off; off += (n + 63) & ~(size_t)63; return o; };
  size_t o_gcn   = alloc((size_t)8192 * DM_);
  size_t o_q     = alloc((size_t)8192 * DM_);
  size_t o_k     = alloc((size_t)8192 * DM_);
  size_t o_adjs  = alloc((size_t)B_ * L_ * L_);
  size_t o_adjag = alloc((size_t)B_ * L_ * L_);
  size_t o_denag = alloc(8192);
  size_t o_dens  = alloc(8192);          // contiguous after denag
  size_t o_t0    = alloc(600);
  size_t o_apos  = alloc(B_ * MAXA);
  size_t o_acnt  = alloc(64);
  size_t o_aspd  = alloc(B_ * MAXA * DK_);
  size_t o_tasp  = alloc(B_ * 8 * MAXA * DK_);
  size_t o_s0    = alloc(B_ * 8 * L_);
  size_t o_avg   = alloc(B_ * 8 * L_);
  size_t o_s0bar = alloc(B_ * L_);
  size_t o_avbar = alloc(B_ * L_);
  size_t o_hg    = alloc(2 * 2 * 4800);  // u32 tagged-h
  size_t o_wqk   = alloc(720000);
  size_t o_bqk   = alloc(1200);
  size_t o_wih   = alloc(864000);
  size_t o_aff   = alloc(180000);
  size_t o_oag1  = alloc((size_t)8192 * 300);
  size_t o_os1   = alloc((size_t)8192 * 300);
  size_t o_big   = alloc(23134300);      // union region
  // union A: embs(2,949,120) + pre_f(9,830,400) + pre_b(9,830,400)
  size_t o_embs = o_big;
  size_t o_pref = o_big + 2949120;
  size_t o_preb = o_pref + 9830400;
  // union B: scores bf16 (16,777,216 float slots)
  size_t o_sc   = o_big;
  // union C: GCN temps
  size_t o_tmp  = o_big;
  size_t o_gag  = o_big + 4915200;
  size_t o_gs   = o_gag + 2457600;
  size_t o_h1   = o_gs  + 2457600;      // h1b = o_h1 + 2457600
  size_t o_a1m  = o_h1  + 4915200;
  size_t o_a2m  = o_a1m + 4194304;

  if (ws_size < off * sizeof(float)) {
    (void)hipMemsetAsync(d_out, 0x7F, (size_t)out_size * sizeof(float), stream);
    return;
  }

  // 0) stage packed weights (wqk | bqk | wih | aff)
  k_stage<<<(1765200 + 255) / 256, 256, 0, stream>>>(
      wq, wk, bq, bk, w_ih_f, w_ih_b, aff1, aff2,
      W + o_wqk, W + o_bqk, W + o_wih, W + o_aff);

  // 1) embeddings -> [t*16+b][360]
  k_embed<<<(L_ * B_ * 360 + 255) / 256, 256, 0, stream>>>(tok, pos, post, emb_w, pos_w, post_w, W + o_embs);

  // 2) pre-GEMMs batched (z=2): preT[j][t*16+b] = w_ih[j] . embs
  gemm(stream, true, W + o_wih, 360, 432000, 0, W + o_embs, 360, 0, 0,
       W + o_pref, nullptr, 8192, 9830400, 0, nullptr, 0, nullptr, 1.f, 0, 1200, 8192, 360, 2, 1);

  // 3) BiLSTM: 76 sharded blocks, tagged-word sync
  k_lstm<<<2 * NCH, 256, 0, stream>>>(W + o_pref, W + o_preb, w_hh_f, w_hh_b,
                                      b_ih_f, b_hh_f, b_ih_b, b_hh_b,
                                      W + o_gcn, (unsigned*)(W + o_hg));

  // 4) q/k batched (z=2)
  gemm(stream, true, W + o_gcn, DM_, 0, 0, W + o_wqk, DM_, 360000, 0,
       W + o_q, nullptr, DM_, (long)(o_k - o_q), 0, W + o_bqk, 600, nullptr,
       1.f, 0, 8192, DM_, DM_, 2, 1);

  // 5) aspect structure
  k_asplist<<<1, 64, 0, stream>>>(asp_mask, (int*)(W + o_apos), (int*)(W + o_acnt));
  k_t0<<<(600 + 255) / 256, 256, 0, stream>>>(bd, wm, W + o_t0);
  k_aspd<<<(B_ * MAXA * DK_ + 255) / 256, 256, 0, stream>>>(W + o_gcn, asp_mask,
      (const int*)(W + o_apos), (const int*)(W + o_acnt), wd, bd, W + o_aspd);
  k_tasp<<<(B_ * 8 * MAXA * DK_ + 255) / 256, 256, 0, stream>>>(W + o_aspd,
      (const int*)(W + o_acnt), wm, W + o_tasp);
  k_avg<<<(B_ * 8 * L_ + 255) / 256, 256, 0, stream>>>(W + o_k, W + o_t0, W + o_tasp,
      (const int*)(W + o_acnt), bias_m, W + o_s0, W + o_avg);
  k_bar<<<(B_ * L_ + 255) / 256, 256, 0, stream>>>(W + o_s0, W + o_avg, W + o_s0bar, W + o_avbar);

  // 6) scores (bf16) -> fused adj_s ; adj_ag
  gemm(stream, true, W + o_q, DM_, (long)L_ * DM_, DK_, W + o_k, DM_, (long)L_ * DM_, DK_,
       nullptr, (bf16*)(W + o_sc), L_, (long)8 * L_ * L_, (long)L_ * L_,
       nullptr, 0, nullptr, 0.1154700538f, 0, L_, L_, DK_, B_, 8);
  k_adjs2<<<B_ * L_, 256, 0, stream>>>((const bf16*)(W + o_sc), tok, W + o_adjs, W + o_dens);
  k_adjag<<<B_ * L_, 256, 0, stream>>>(asp_mask, adjr, W + o_s0bar, W + o_avbar,
                                       W + o_adjag, W + o_denag);

  // 7) two GCN layers
  const float* waL[2] = {wa0, wa1};
  const float* baL[2] = {ba0, ba1};
  const float* wsL[2] = {ws0, ws1};
  const float* bsL[2] = {bs0, bs1};
  const float* inAg = W + o_gcn;
  const float* inS  = W + o_gcn;
  int D = DM_;
  for (int layer = 0; layer < 2; ++layer) {
    long sInB1 = (layer == 0) ? 0 : (long)(o_os1 - o_oag1);
    // stage-1: tmp = adj @ in  (ag path then s path)
    gemm(stream, false, W + o_adjag, L_, (long)L_ * L_, 0, inAg, D, (long)L_ * D, 0,
         W + o_tmp, nullptr, D, (long)L_ * D, 0, nullptr, 0, nullptr, 1.f, 0, L_, D, L_, B_, 1);
    gemm(stream, true, W + o_tmp, D, 0, 0, waL[layer], D, 0, 0,
         W + o_gag, nullptr, 300, 0, 0, baL[layer], 0, W + o_denag, 1.f, 1, 8192, 300, D, 1, 1);
    gemm(stream, false, W + o_adjs, L_, (long)L_ * L_, 0, inS, D, (long)L_ * D, 0,
         W + o_tmp, nullptr, D, (long)L_ * D, 0, nullptr, 0, nullptr, 1.f, 0, L_, D, L_, B_, 1);
    gemm(stream, true, W + o_tmp, D, 0, 0, wsL[layer], D, 0, 0,
         W + o_gs, nullptr, 300, 0, 0, bsL[layer], 0, W + o_dens, 1.f, 1, 8192, 300, D, 1, 1);
    // affine batched (z=2): h1 = gag@aff1 ; h1b = gs@aff2
    gemm(stream, false, W + o_gag, 300, (long)(o_gs - o_gag), 0, W + o_aff, 300, 90000, 0,
         W + o_h1, nullptr, 300, 2457600, 0, nullptr, 0, nullptr, 1.f, 0, 8192, 300, 300, 2, 1);
    // A1/A2 batched (z=2x16): a1m = h1 @ gs^T ; a2m = h1b @ gag^T
    gemm(stream, true, W + o_h1, 300, 2457600, (long)L_ * 300,
         W + o_gs, 300, (long)o_gag - (long)o_gs, (long)L_ * 300,
         W + o_a1m, nullptr, L_, 4194304, (long)L_ * L_,
         nullptr, 0, nullptr, 1.f, 0, L_, L_, 300, 2, B_);
    k_softmax<<<2 * B_ * L_, 256, 0, stream>>>(W + o_a1m);
    // out batched (z=2x16): out_ag = A1 @ gs ; out_s = A2 @ gag
    float* dstC; int ldcO; long sC1o, sC2o;
    if (layer == 0) { dstC = W + o_oag1; ldcO = 300; sC1o = (long)(o_os1 - o_oag1); sC2o = (long)L_ * 300; }
    else            { dstC = out;        ldcO = 600; sC1o = 300;                    sC2o = (long)L_ * 600; }
    gemm(stream, false, W + o_a1m, L_, 4194304, (long)L_ * L_,
         W + o_gs, 300, (long)o_gag - (long)o_gs, (long)L_ * 300,
         dstC, nullptr, ldcO, sC1o, sC2o,
         nullptr, 0, nullptr, 1.f, 0, L_, 300, L_, 2, B_);
    inAg = W + o_oag1;
    inS  = W + o_os1;
    D = 300;
  }
}